// Round 3
// baseline (10418.736 us; speedup 1.0000x reference)
//
#include <hip/hip_runtime.h>
#include <hip/hip_bf16.h>
#include <hip/hip_cooperative_groups.h>

namespace cg = cooperative_groups;

typedef short s8v __attribute__((ext_vector_type(8)));   // 8 bf16 (4 VGPRs) MFMA frag
typedef float f4v __attribute__((ext_vector_type(4)));   // MFMA accum frag / float4 load

#define NBLK 192   // 6 stages * 32 blocks

typedef unsigned short u16;

__device__ __forceinline__ float b2f(u16 u) {
  union { unsigned int i; float f; } v; v.i = ((unsigned int)u) << 16; return v.f;
}
__device__ __forceinline__ u16 f2b(float f) {
  union { float f; unsigned int i; } v; v.f = f;
  unsigned int x = v.i;
  return (u16)((x + 0x7fffu + ((x >> 16) & 1u)) >> 16);  // RNE
}
__device__ __forceinline__ s8v cvt8(f4v a, f4v b) {
  s8v r;
  r[0] = (short)f2b(a[0]); r[1] = (short)f2b(a[1]);
  r[2] = (short)f2b(a[2]); r[3] = (short)f2b(a[3]);
  r[4] = (short)f2b(b[0]); r[5] = (short)f2b(b[1]);
  r[6] = (short)f2b(b[2]); r[7] = (short)f2b(b[3]);
  return r;
}

// ---------------------------------------------------------------------------
// P1: build transposed bf16 weights from float32 sources.
// WT[stage][col 0..2047][k 0..1023] (bf16), stage = d*3+l:
//   l==0 : k<512 -> rec[d][0][k][col];  k-512 in [0,300) -> k0[d][k-512][col]; else 0
//   l>=1 : k<512 -> k12[d][l-1][k][col]; else rec[d][l][k-512][col]
// WaT[n][k] = Wa0[k][n];  WdT likewise for Wd0.
// ---------------------------------------------------------------------------
__global__ __launch_bounds__(256) void prep_weights(
    const float* __restrict__ k0, const float* __restrict__ k12,
    const float* __restrict__ rec, const float* __restrict__ Wa0,
    const float* __restrict__ Wd0,
    u16* __restrict__ WT, u16* __restrict__ WaT, u16* __restrict__ WdT)
{
  __shared__ u16 tl[64][65];
  int bid = blockIdx.x, tid = threadIdx.x;
  if (bid < 3072) {
    int stage = bid >> 9;
    int t2 = bid & 511;
    int ct = t2 >> 4, kt = t2 & 15;
    int d = stage / 3, l = stage - 3 * d;
    int colbase = ct * 64, kbase = kt * 64;
    int cl = tid & 63;
#pragma unroll
    for (int i = 0; i < 16; ++i) {
      int kl = i * 4 + (tid >> 6);
      int k = kbase + kl, col = colbase + cl;
      float v;
      if (l == 0) {
        if (k < 512) v = rec[((size_t)(d * 3 + 0) * 512 + k) * 2048 + col];
        else { int j = k - 512; v = (j < 300) ? k0[((size_t)d * 300 + j) * 2048 + col] : 0.f; }
      } else {
        if (k < 512) v = k12[((size_t)(d * 2 + (l - 1)) * 512 + k) * 2048 + col];
        else         v = rec[((size_t)(d * 3 + l) * 512 + (k - 512)) * 2048 + col];
      }
      tl[kl][cl] = f2b(v);
    }
    __syncthreads();
#pragma unroll
    for (int i = 0; i < 16; ++i) {
      int cl2 = i * 4 + (tid >> 6);
      int kl2 = tid & 63;
      WT[((size_t)stage * 2048 + colbase + cl2) * 1024 + kbase + kl2] = tl[kl2][cl2];
    }
  } else {
    int m = bid - 3072;
    int mat = m >> 5, tt = m & 31;
    int nt = tt & 3, kt = tt >> 2;
    const float* src = mat ? Wd0 : Wa0;
    u16* dst = mat ? WdT : WaT;
    int nbase = nt * 64, kbase = kt * 64;
    int cl = tid & 63;
#pragma unroll
    for (int i = 0; i < 16; ++i) {
      int kl = i * 4 + (tid >> 6);
      tl[kl][cl] = f2b(src[(size_t)(kbase + kl) * 256 + nbase + cl]);
    }
    __syncthreads();
#pragma unroll
    for (int i = 0; i < 16; ++i) {
      int nl = i * 4 + (tid >> 6);
      int kl = tid & 63;
      dst[(size_t)(nbase + nl) * 512 + kbase + kl] = tl[kl][nl];
    }
  }
}

// ---------------------------------------------------------------------------
// Main persistent LSTM kernel.  192 blocks: stage = bid>>5 (d*3+l), slice = bid&31.
// Block owns units [u0,u0+16), computes the 4 gate tiles for those units.
// Pipeline: step s, layer l processes t = s-l.  Uniform K=1024:
//   l==0: k<512 = rec (A=h1[t-1]);  k>=512 = k0-padded (A=emb row float, direct)
//   l>=1: k<512 = k12 (A=h_{l-1}[t]); k>=512 = rec (A=h_l[t-1])
// 4 waves K-split 256 each; B-frags permanently in 128 VGPRs.
// ---------------------------------------------------------------------------
__global__ __launch_bounds__(256, 1) void lstm_main(
    const u16* __restrict__ WT, const float* __restrict__ emb,
    const int* __restrict__ ids, const float* __restrict__ bias,
    u16* __restrict__ hbuf, u16* __restrict__ out3)
{
  cg::grid_group grid = cg::this_grid();
  __shared__ float lpart[4][48][68];   // [src wave][3 m-tiles *16][64 cols+pad]
  const int tid = threadIdx.x;
  const int w = tid >> 6;            // wave id (K-split, and cell-update row group)
  const int lane = tid & 63;
  const int lm = lane & 15, qk = lane >> 4;
  const int bid = blockIdx.x;
  const int stage = bid >> 5;
  const int slice = bid & 31;
  const int u0 = slice * 16;
  const int d = stage / 3, l = stage - 3 * d;

  // B fragments: col = nt*512 + u0 + lm (gate nt), k = w*256 + ks*32 + qk*8
  s8v bfr[8][4];
#pragma unroll
  for (int ks = 0; ks < 8; ++ks)
#pragma unroll
    for (int nt = 0; nt < 4; ++nt)
      bfr[ks][nt] = *(const s8v*)(WT + ((size_t)stage * 2048 + nt * 512 + u0 + lm) * 1024
                                  + w * 256 + ks * 32 + qk * 8);
  float bias4[4];
#pragma unroll
  for (int nt = 0; nt < 4; ++nt)
    bias4[nt] = bias[((size_t)d * 3 + l) * 2048 + nt * 512 + u0 + lm];

  float c[4] = {0.f, 0.f, 0.f, 0.f};      // cell state, rows 16w+qk*4+r, unit u0+lm
  const int brow = 16 * w + qk * 4;
  const int uu = u0 + lm;
  const f4v fzero = {0.f, 0.f, 0.f, 0.f};

  for (int s = 0; s < 258; ++s) {
    int t = s - l;
    if (t >= 0 && t < 256) {
      int p = (s - 1) & 1;               // reads from parity (s-1)&1, writes to s&1
      int tx = d ? (255 - t) : t;        // time index into input sequence
      const u16* lo;
      const u16* hi;
      if (l == 0) {
        lo = hbuf + ((size_t)p * 6 + stage) * 64 * 512;          // h1[t-1]
        hi = lo;                                                  // unused (emb path)
      } else {
        lo = hbuf + ((size_t)p * 6 + (stage - 1)) * 64 * 512;     // h_{l-1}[t]
        hi = hbuf + ((size_t)p * 6 + stage) * 64 * 512;           // h_l[t-1]
      }

      f4v acc[4][4];
#pragma unroll
      for (int mt = 0; mt < 4; ++mt)
#pragma unroll
        for (int nt = 0; nt < 4; ++nt) acc[mt][nt] = fzero;

      if (l == 0 && w >= 2) {
        // ---- input-projection side: A = emb[ids[row][tx]] (float row, 16B aligned:
        //      row byte offset = id*1200, 1200 = 75*16) ----
        if (w == 2) {                    // j in [0,256): all fragments fully valid
#pragma unroll
          for (int mt = 0; mt < 4; ++mt) {
            const int id = ids[(mt * 16 + lm) * 256 + tx];
            const float* er = emb + (size_t)id * 300;
#pragma unroll
            for (int ks = 0; ks < 8; ++ks) {
              f4v f0 = *(const f4v*)(er + ks * 32 + qk * 8);
              f4v f1 = *(const f4v*)(er + ks * 32 + qk * 8 + 4);
              s8v a = cvt8(f0, f1);
#pragma unroll
              for (int nt = 0; nt < 4; ++nt)
                acc[mt][nt] = __builtin_amdgcn_mfma_f32_16x16x32_bf16(a, bfr[ks][nt], acc[mt][nt], 0, 0, 0);
            }
          }
        } else {                         // w==3: j in [256,512); only ks 0,1 nonzero
#pragma unroll
          for (int mt = 0; mt < 4; ++mt) {
            const int id = ids[(mt * 16 + lm) * 256 + tx];
            const float* er = emb + (size_t)id * 300;
            {                            // ks=0: j 256..287 all valid
              f4v f0 = *(const f4v*)(er + 256 + qk * 8);
              f4v f1 = *(const f4v*)(er + 256 + qk * 8 + 4);
              s8v a0 = cvt8(f0, f1);
#pragma unroll
              for (int nt = 0; nt < 4; ++nt)
                acc[mt][nt] = __builtin_amdgcn_mfma_f32_16x16x32_bf16(a0, bfr[0][nt], acc[mt][nt], 0, 0, 0);
            }
            {                            // ks=1: j 288..319; valid only j<300
              s8v a1;
              if (qk == 0) {             // j 288..295
                f4v f0 = *(const f4v*)(er + 288);
                f4v f1 = *(const f4v*)(er + 292);
                a1 = cvt8(f0, f1);
              } else if (qk == 1) {      // j 296..303: 296..299 valid, rest zero
                f4v f0 = *(const f4v*)(er + 296);
                a1 = cvt8(f0, fzero);
              } else {                   // j >= 304: WT rows are zero anyway
                a1 = (s8v){0,0,0,0,0,0,0,0};
              }
#pragma unroll
              for (int nt = 0; nt < 4; ++nt)
                acc[mt][nt] = __builtin_amdgcn_mfma_f32_16x16x32_bf16(a1, bfr[1][nt], acc[mt][nt], 0, 0, 0);
            }
            // ks 2..7 contribute zero (WT rows >= 832 are 0): skipped
          }
        }
      } else {
        // ---- standard h-side path ----
        const u16* aptr = (w < 2) ? lo : hi;
        const int koff = (w & 1) * 256;
#pragma unroll
        for (int ks = 0; ks < 8; ++ks) {
#pragma unroll
          for (int mt = 0; mt < 4; ++mt) {
            s8v a = *(const s8v*)(aptr + (size_t)(mt * 16 + lm) * 512 + koff + ks * 32 + qk * 8);
#pragma unroll
            for (int nt = 0; nt < 4; ++nt)
              acc[mt][nt] = __builtin_amdgcn_mfma_f32_16x16x32_bf16(a, bfr[ks][nt], acc[mt][nt], 0, 0, 0);
          }
        }
      }

      // cross-wave K reduction: wave w keeps m-tile w, ships the other three
#pragma unroll
      for (int mt = 0; mt < 4; ++mt) {
        if (mt == w) continue;
        int slot = mt - (mt > w ? 1 : 0);
#pragma unroll
        for (int nt = 0; nt < 4; ++nt)
#pragma unroll
          for (int r = 0; r < 4; ++r)
            lpart[w][slot * 16 + qk * 4 + r][nt * 16 + lm] = acc[mt][nt][r];
      }
      __syncthreads();

      float z[4][4];
#pragma unroll
      for (int nt = 0; nt < 4; ++nt)
#pragma unroll
        for (int r = 0; r < 4; ++r) {
          float v = acc[w][nt][r];
#pragma unroll
          for (int ps = 0; ps < 4; ++ps) {
            if (ps == w) continue;
            int slot = w - (w > ps ? 1 : 0);
            v += lpart[ps][slot * 16 + qk * 4 + r][nt * 16 + lm];
          }
          z[nt][r] = v + bias4[nt];
        }

      // cell update: i,f,g,o = z[0..3]
      u16* hout = hbuf + ((size_t)(s & 1) * 6 + stage) * 64 * 512;
      u16* o3 = out3 + ((size_t)d * 256 + t) * 64 * 512;
#pragma unroll
      for (int r = 0; r < 4; ++r) {
        float zi = z[0][r], zf = z[1][r], zg = z[2][r], zo = z[3][r];
        float si = 1.f / (1.f + __expf(-zi));
        float sf = 1.f / (1.f + __expf(-zf));
        float so = 1.f / (1.f + __expf(-zo));
        float sg = zg / (1.f + fabsf(zg));
        float cn = sf * c[r] + si * sg;
        c[r] = cn;
        float h = so * (cn / (1.f + fabsf(cn)));
        u16 hb = f2b(h);
        size_t off = (size_t)(brow + r) * 512 + uu;
        hout[off] = hb;
        if (l == 2) o3[off] = hb;
      }
      __syncthreads();   // lpart reuse safety within the step
    }
    grid.sync();
  }
}

// ---------------------------------------------------------------------------
// Attention scores: per t-block, enc = 0.5*(out3[0][t]+out3[1][t]) on the fly,
// a = prelu(enc@Wa0+ba0), scores[b][t] = a@Wa1 + ba1.
// ---------------------------------------------------------------------------
__global__ __launch_bounds__(256) void attn_scores(
    const u16* __restrict__ out3, const u16* __restrict__ WaT,
    const float* __restrict__ ba0, const float* __restrict__ alpha_a,
    const float* __restrict__ Wa1, const float* __restrict__ ba1,
    float* __restrict__ scores)
{
  int t = blockIdx.x, tid = threadIdx.x;
  int w = tid >> 6, lane = tid & 63, lm = lane & 15, qk = lane >> 4;
  const u16* e0 = out3 + (size_t)t * 64 * 512;
  const u16* e1 = out3 + ((size_t)256 + t) * 64 * 512;
  const f4v fzero = {0.f, 0.f, 0.f, 0.f};
  f4v acc[16];
#pragma unroll
  for (int nt = 0; nt < 16; ++nt) acc[nt] = fzero;

  for (int ks = 0; ks < 16; ++ks) {
    size_t aoff = (size_t)(16 * w + lm) * 512 + ks * 32 + qk * 8;
    s8v a0 = *(const s8v*)(e0 + aoff);
    s8v a1 = *(const s8v*)(e1 + aoff);
    s8v af;
#pragma unroll
    for (int j = 0; j < 8; ++j)
      af[j] = (short)f2b(0.5f * (b2f((u16)a0[j]) + b2f((u16)a1[j])));
#pragma unroll
    for (int nt = 0; nt < 16; ++nt) {
      s8v bf = *(const s8v*)(WaT + (size_t)(nt * 16 + lm) * 512 + ks * 32 + qk * 8);
      acc[nt] = __builtin_amdgcn_mfma_f32_16x16x32_bf16(af, bf, acc[nt], 0, 0, 0);
    }
  }

  float sums[4] = {0.f, 0.f, 0.f, 0.f};
#pragma unroll
  for (int nt = 0; nt < 16; ++nt) {
    int col = nt * 16 + lm;
    float bb = ba0[col];
    float al = alpha_a[col];
    float wv = Wa1[col];
#pragma unroll
    for (int r = 0; r < 4; ++r) {
      float v = acc[nt][r] + bb;
      v = (v >= 0.f) ? v : al * v;
      sums[r] += v * wv;
    }
  }
  float bb1 = ba1[0];
#pragma unroll
  for (int r = 0; r < 4; ++r) {
    float v = sums[r];
    v += __shfl_xor(v, 1, 16);
    v += __shfl_xor(v, 2, 16);
    v += __shfl_xor(v, 4, 16);
    v += __shfl_xor(v, 8, 16);
    if (lm == 0) {
      int b = 16 * w + qk * 4 + r;
      scores[(size_t)b * 256 + t] = v + bb1;
    }
  }
}

// ---------------------------------------------------------------------------
// Softmax over T + pooled[b][u] = sum_t w[t]*enc[b][t][u]
// ---------------------------------------------------------------------------
__global__ __launch_bounds__(256) void attn_pool(
    const u16* __restrict__ out3, const float* __restrict__ scores,
    u16* __restrict__ pooled)
{
  __shared__ float red[256];
  __shared__ float wts[256];
  int b = blockIdx.x, tid = threadIdx.x;
  float s = scores[(size_t)b * 256 + tid];
  red[tid] = s; __syncthreads();
  for (int o = 128; o > 0; o >>= 1) { if (tid < o) red[tid] = fmaxf(red[tid], red[tid + o]); __syncthreads(); }
  float m = red[0]; __syncthreads();
  float e = __expf(s - m);
  red[tid] = e; __syncthreads();
  for (int o = 128; o > 0; o >>= 1) { if (tid < o) red[tid] += red[tid + o]; __syncthreads(); }
  float inv = 1.f / red[0];
  wts[tid] = e * inv; __syncthreads();

  int u2 = tid * 2;
  float a0 = 0.f, a1 = 0.f;
#pragma unroll 4
  for (int t = 0; t < 256; ++t) {
    float wt = wts[t];
    const ushort2 v0 = *(const ushort2*)(out3 + ((size_t)t * 64 + b) * 512 + u2);
    const ushort2 v1 = *(const ushort2*)(out3 + (((size_t)256 + t) * 64 + b) * 512 + u2);
    a0 += wt * 0.5f * (b2f(v0.x) + b2f(v1.x));
    a1 += wt * 0.5f * (b2f(v0.y) + b2f(v1.y));
  }
  pooled[(size_t)b * 512 + u2] = f2b(a0);
  pooled[(size_t)b * 512 + u2 + 1] = f2b(a1);
}

// ---------------------------------------------------------------------------
// Head: h = prelu(BN(pooled@Wd0+bd0)); out = softmax(h@Wd1+bd1)  (float out)
// ---------------------------------------------------------------------------
__global__ __launch_bounds__(256) void head(
    const u16* __restrict__ pooled, const u16* __restrict__ WdT,
    const float* __restrict__ bd0, const float* __restrict__ gamma,
    const float* __restrict__ beta, const float* __restrict__ bn_mean,
    const float* __restrict__ bn_var, const float* __restrict__ alpha_h,
    const float* __restrict__ Wd1, const float* __restrict__ bd1,
    float* __restrict__ outp)
{
  __shared__ float hl[64][260];
  __shared__ float lg[64][8];
  int tid = threadIdx.x;
  int w = tid >> 6, lane = tid & 63, lm = lane & 15, qk = lane >> 4;
  const f4v fzero = {0.f, 0.f, 0.f, 0.f};
  f4v acc[16];
#pragma unroll
  for (int nt = 0; nt < 16; ++nt) acc[nt] = fzero;
  for (int ks = 0; ks < 16; ++ks) {
    s8v a = *(const s8v*)(pooled + (size_t)(16 * w + lm) * 512 + ks * 32 + qk * 8);
#pragma unroll
    for (int nt = 0; nt < 16; ++nt) {
      s8v bf = *(const s8v*)(WdT + (size_t)(nt * 16 + lm) * 512 + ks * 32 + qk * 8);
      acc[nt] = __builtin_amdgcn_mfma_f32_16x16x32_bf16(a, bf, acc[nt], 0, 0, 0);
    }
  }
#pragma unroll
  for (int nt = 0; nt < 16; ++nt) {
    int col = nt * 16 + lm;
    float mn = bn_mean[col];
    float sc = gamma[col] * rsqrtf(bn_var[col] + 1e-3f);
    float be = beta[col];
    float al = alpha_h[col];
    float b0 = bd0[col];
#pragma unroll
    for (int r = 0; r < 4; ++r) {
      float v = acc[nt][r] + b0;
      v = (v - mn) * sc + be;
      v = (v >= 0.f) ? v : al * v;
      hl[16 * w + qk * 4 + r][col] = v;
    }
  }
  __syncthreads();
  for (int idx = tid; idx < 448; idx += 256) {
    int b = idx / 7, cc = idx - b * 7;
    float sv = bd1[cc];
    for (int k = 0; k < 256; ++k) sv += hl[b][k] * Wd1[k * 7 + cc];
    lg[b][cc] = sv;
  }
  __syncthreads();
  if (tid < 64) {
    float mx = -1e30f;
#pragma unroll
    for (int cc = 0; cc < 7; ++cc) mx = fmaxf(mx, lg[tid][cc]);
    float sum = 0.f; float ex[7];
#pragma unroll
    for (int cc = 0; cc < 7; ++cc) { ex[cc] = __expf(lg[tid][cc] - mx); sum += ex[cc]; }
    float inv = 1.f / sum;
#pragma unroll
    for (int cc = 0; cc < 7; ++cc) outp[tid * 7 + cc] = ex[cc] * inv;
  }
}

// ---------------------------------------------------------------------------
extern "C" void kernel_launch(void* const* d_in, const int* in_sizes, int n_in,
                              void* d_out, int out_size, void* d_ws, size_t ws_size,
                              hipStream_t stream)
{
  (void)in_sizes; (void)n_in; (void)out_size; (void)ws_size;
  const int*   ids     = (const int*)d_in[0];
  const float* emb     = (const float*)d_in[1];
  const float* k0      = (const float*)d_in[2];
  const float* k12     = (const float*)d_in[3];
  const float* rec     = (const float*)d_in[4];
  const float* bias    = (const float*)d_in[5];
  const float* Wa0     = (const float*)d_in[6];
  const float* ba0     = (const float*)d_in[7];
  const float* alpha_a = (const float*)d_in[8];
  const float* Wa1     = (const float*)d_in[9];
  const float* ba1     = (const float*)d_in[10];
  const float* Wd0     = (const float*)d_in[11];
  const float* bd0     = (const float*)d_in[12];
  const float* gamma   = (const float*)d_in[13];
  const float* beta    = (const float*)d_in[14];
  const float* bn_mean = (const float*)d_in[15];
  const float* bn_var  = (const float*)d_in[16];
  const float* alpha_h = (const float*)d_in[17];
  const float* Wd1     = (const float*)d_in[18];
  const float* bd1     = (const float*)d_in[19];

  char* ws = (char*)d_ws;
  u16* WT      = (u16*)(ws);                    // 6*2048*1024*2   = 25,165,824
  u16* hbuf    = (u16*)(ws + 25165824);         // 2*6*64*512*2    =    786,432
  u16* out3    = (u16*)(ws + 25952256);         // 2*256*64*512*2  = 33,554,432
  u16* WaT     = (u16*)(ws + 59506688);         //                 =    262,144
  u16* WdT     = (u16*)(ws + 59768832);         //                 =    262,144
  float* scores= (float*)(ws + 60030976);       // 64*256*4        =     65,536
  u16* pooled  = (u16*)(ws + 60096512);         // 64*512*2        =     65,536
                                                // total             60,162,048 B

  hipMemsetAsync(hbuf, 0, 786432, stream);

  prep_weights<<<dim3(3136), dim3(256), 0, stream>>>(k0, k12, rec, Wa0, Wd0, WT, WaT, WdT);

  void* args[] = { (void*)&WT, (void*)&emb, (void*)&ids, (void*)&bias, (void*)&hbuf, (void*)&out3 };
  hipLaunchCooperativeKernel((void*)lstm_main, dim3(NBLK), dim3(256), args, 0, stream);

  attn_scores<<<dim3(256), dim3(256), 0, stream>>>(out3, WaT, ba0, alpha_a, Wa1, ba1, scores);
  attn_pool<<<dim3(64), dim3(256), 0, stream>>>(out3, scores, pooled);
  head<<<dim3(1), dim3(256), 0, stream>>>(pooled, WdT, bd0, gamma, beta, bn_mean, bn_var,
                                          alpha_h, Wd1, bd1, (float*)d_out);
}

// Round 4
// 7623.302 us; speedup vs baseline: 1.3667x; 1.3667x over previous
//
#include <hip/hip_runtime.h>
#include <hip/hip_bf16.h>

typedef short s8v __attribute__((ext_vector_type(8)));   // 8 bf16 (4 VGPRs) MFMA frag
typedef float f4v __attribute__((ext_vector_type(4)));   // MFMA accum frag / float4 load

#define NBLK 192   // 6 stages * 32 blocks

typedef unsigned short u16;

__device__ __forceinline__ float b2f(u16 u) {
  union { unsigned int i; float f; } v; v.i = ((unsigned int)u) << 16; return v.f;
}
__device__ __forceinline__ u16 f2b(float f) {
  union { float f; unsigned int i; } v; v.f = f;
  unsigned int x = v.i;
  return (u16)((x + 0x7fffu + ((x >> 16) & 1u)) >> 16);  // RNE
}
__device__ __forceinline__ s8v cvt8(f4v a, f4v b) {
  s8v r;
  r[0] = (short)f2b(a[0]); r[1] = (short)f2b(a[1]);
  r[2] = (short)f2b(a[2]); r[3] = (short)f2b(a[3]);
  r[4] = (short)f2b(b[0]); r[5] = (short)f2b(b[1]);
  r[6] = (short)f2b(b[2]); r[7] = (short)f2b(b[3]);
  return r;
}

// ---------------------------------------------------------------------------
// Lightweight agent-scope grid barrier (monotone counter, no system-scope
// flush — this is the entire round-4 change).  Release fence = s_waitcnt +
// buffer_wbl2 (dirty L2 -> LLC, ~0.5 MB/step); acquire fence = buffer_inv.
// ---------------------------------------------------------------------------
__device__ __forceinline__ void grid_bar(unsigned* cnt, unsigned target) {
  __syncthreads();
  if (threadIdx.x == 0) {
    __builtin_amdgcn_fence(__ATOMIC_RELEASE, "agent");   // h stores -> LLC
    __hip_atomic_fetch_add(cnt, 1u, __ATOMIC_RELAXED, __HIP_MEMORY_SCOPE_AGENT);
    while (__hip_atomic_load(cnt, __ATOMIC_RELAXED, __HIP_MEMORY_SCOPE_AGENT) < target)
      __builtin_amdgcn_s_sleep(2);
    __builtin_amdgcn_fence(__ATOMIC_ACQUIRE, "agent");   // invalidate L2 before h reads
  }
  __syncthreads();
}

// ---------------------------------------------------------------------------
// P1: build transposed bf16 weights from float32 sources.
// WT[stage][col 0..2047][k 0..1023] (bf16), stage = d*3+l:
//   l==0 : k<512 -> rec[d][0][k][col];  k-512 in [0,300) -> k0[d][k-512][col]; else 0
//   l>=1 : k<512 -> k12[d][l-1][k][col]; else rec[d][l][k-512][col]
// WaT[n][k] = Wa0[k][n];  WdT likewise for Wd0.
// ---------------------------------------------------------------------------
__global__ __launch_bounds__(256) void prep_weights(
    const float* __restrict__ k0, const float* __restrict__ k12,
    const float* __restrict__ rec, const float* __restrict__ Wa0,
    const float* __restrict__ Wd0,
    u16* __restrict__ WT, u16* __restrict__ WaT, u16* __restrict__ WdT)
{
  __shared__ u16 tl[64][65];
  int bid = blockIdx.x, tid = threadIdx.x;
  if (bid < 3072) {
    int stage = bid >> 9;
    int t2 = bid & 511;
    int ct = t2 >> 4, kt = t2 & 15;
    int d = stage / 3, l = stage - 3 * d;
    int colbase = ct * 64, kbase = kt * 64;
    int cl = tid & 63;
#pragma unroll
    for (int i = 0; i < 16; ++i) {
      int kl = i * 4 + (tid >> 6);
      int k = kbase + kl, col = colbase + cl;
      float v;
      if (l == 0) {
        if (k < 512) v = rec[((size_t)(d * 3 + 0) * 512 + k) * 2048 + col];
        else { int j = k - 512; v = (j < 300) ? k0[((size_t)d * 300 + j) * 2048 + col] : 0.f; }
      } else {
        if (k < 512) v = k12[((size_t)(d * 2 + (l - 1)) * 512 + k) * 2048 + col];
        else         v = rec[((size_t)(d * 3 + l) * 512 + (k - 512)) * 2048 + col];
      }
      tl[kl][cl] = f2b(v);
    }
    __syncthreads();
#pragma unroll
    for (int i = 0; i < 16; ++i) {
      int cl2 = i * 4 + (tid >> 6);
      int kl2 = tid & 63;
      WT[((size_t)stage * 2048 + colbase + cl2) * 1024 + kbase + kl2] = tl[kl2][cl2];
    }
  } else {
    int m = bid - 3072;
    int mat = m >> 5, tt = m & 31;
    int nt = tt & 3, kt = tt >> 2;
    const float* src = mat ? Wd0 : Wa0;
    u16* dst = mat ? WdT : WaT;
    int nbase = nt * 64, kbase = kt * 64;
    int cl = tid & 63;
#pragma unroll
    for (int i = 0; i < 16; ++i) {
      int kl = i * 4 + (tid >> 6);
      tl[kl][cl] = f2b(src[(size_t)(kbase + kl) * 256 + nbase + cl]);
    }
    __syncthreads();
#pragma unroll
    for (int i = 0; i < 16; ++i) {
      int nl = i * 4 + (tid >> 6);
      int kl = tid & 63;
      dst[(size_t)(nbase + nl) * 512 + kbase + kl] = tl[kl][nl];
    }
  }
}

// ---------------------------------------------------------------------------
// Main persistent LSTM kernel.  192 blocks: stage = bid>>5 (d*3+l), slice = bid&31.
// Block owns units [u0,u0+16), computes the 4 gate tiles for those units.
// Pipeline: step s, layer l processes t = s-l.  Uniform K=1024:
//   l==0: k<512 = rec (A=h1[t-1]);  k>=512 = k0-padded (A=emb row float, direct)
//   l>=1: k<512 = k12 (A=h_{l-1}[t]); k>=512 = rec (A=h_l[t-1])
// 4 waves K-split 256 each; B-frags permanently in 128 VGPRs.
// ---------------------------------------------------------------------------
__global__ __launch_bounds__(256, 1) void lstm_main(
    const u16* __restrict__ WT, const float* __restrict__ emb,
    const int* __restrict__ ids, const float* __restrict__ bias,
    u16* __restrict__ hbuf, u16* __restrict__ out3, unsigned* __restrict__ bar)
{
  __shared__ float lpart[4][48][68];   // [src wave][3 m-tiles *16][64 cols+pad]
  const int tid = threadIdx.x;
  const int w = tid >> 6;            // wave id (K-split, and cell-update row group)
  const int lane = tid & 63;
  const int lm = lane & 15, qk = lane >> 4;
  const int bid = blockIdx.x;
  const int stage = bid >> 5;
  const int slice = bid & 31;
  const int u0 = slice * 16;
  const int d = stage / 3, l = stage - 3 * d;

  // B fragments: col = nt*512 + u0 + lm (gate nt), k = w*256 + ks*32 + qk*8
  s8v bfr[8][4];
#pragma unroll
  for (int ks = 0; ks < 8; ++ks)
#pragma unroll
    for (int nt = 0; nt < 4; ++nt)
      bfr[ks][nt] = *(const s8v*)(WT + ((size_t)stage * 2048 + nt * 512 + u0 + lm) * 1024
                                  + w * 256 + ks * 32 + qk * 8);
  float bias4[4];
#pragma unroll
  for (int nt = 0; nt < 4; ++nt)
    bias4[nt] = bias[((size_t)d * 3 + l) * 2048 + nt * 512 + u0 + lm];

  float c[4] = {0.f, 0.f, 0.f, 0.f};      // cell state, rows 16w+qk*4+r, unit u0+lm
  const int brow = 16 * w + qk * 4;
  const int uu = u0 + lm;
  const f4v fzero = {0.f, 0.f, 0.f, 0.f};

  for (int s = 0; s < 258; ++s) {
    int t = s - l;
    if (t >= 0 && t < 256) {
      int p = (s - 1) & 1;               // reads from parity (s-1)&1, writes to s&1
      int tx = d ? (255 - t) : t;        // time index into input sequence
      const u16* lo;
      const u16* hi;
      if (l == 0) {
        lo = hbuf + ((size_t)p * 6 + stage) * 64 * 512;          // h1[t-1]
        hi = lo;                                                  // unused (emb path)
      } else {
        lo = hbuf + ((size_t)p * 6 + (stage - 1)) * 64 * 512;     // h_{l-1}[t]
        hi = hbuf + ((size_t)p * 6 + stage) * 64 * 512;           // h_l[t-1]
      }

      f4v acc[4][4];
#pragma unroll
      for (int mt = 0; mt < 4; ++mt)
#pragma unroll
        for (int nt = 0; nt < 4; ++nt) acc[mt][nt] = fzero;

      if (l == 0 && w >= 2) {
        // ---- input-projection side: A = emb[ids[row][tx]] (float row, 16B aligned:
        //      row byte offset = id*1200, 1200 = 75*16) ----
        if (w == 2) {                    // j in [0,256): all fragments fully valid
#pragma unroll
          for (int mt = 0; mt < 4; ++mt) {
            const int id = ids[(mt * 16 + lm) * 256 + tx];
            const float* er = emb + (size_t)id * 300;
#pragma unroll
            for (int ks = 0; ks < 8; ++ks) {
              f4v f0 = *(const f4v*)(er + ks * 32 + qk * 8);
              f4v f1 = *(const f4v*)(er + ks * 32 + qk * 8 + 4);
              s8v a = cvt8(f0, f1);
#pragma unroll
              for (int nt = 0; nt < 4; ++nt)
                acc[mt][nt] = __builtin_amdgcn_mfma_f32_16x16x32_bf16(a, bfr[ks][nt], acc[mt][nt], 0, 0, 0);
            }
          }
        } else {                         // w==3: j in [256,512); only ks 0,1 nonzero
#pragma unroll
          for (int mt = 0; mt < 4; ++mt) {
            const int id = ids[(mt * 16 + lm) * 256 + tx];
            const float* er = emb + (size_t)id * 300;
            {                            // ks=0: j 256..287 all valid
              f4v f0 = *(const f4v*)(er + 256 + qk * 8);
              f4v f1 = *(const f4v*)(er + 256 + qk * 8 + 4);
              s8v a0 = cvt8(f0, f1);
#pragma unroll
              for (int nt = 0; nt < 4; ++nt)
                acc[mt][nt] = __builtin_amdgcn_mfma_f32_16x16x32_bf16(a0, bfr[0][nt], acc[mt][nt], 0, 0, 0);
            }
            {                            // ks=1: j 288..319; valid only j<300
              s8v a1;
              if (qk == 0) {             // j 288..295
                f4v f0 = *(const f4v*)(er + 288);
                f4v f1 = *(const f4v*)(er + 292);
                a1 = cvt8(f0, f1);
              } else if (qk == 1) {      // j 296..303: 296..299 valid, rest zero
                f4v f0 = *(const f4v*)(er + 296);
                a1 = cvt8(f0, fzero);
              } else {                   // j >= 304: WT rows are zero anyway
                a1 = (s8v){0,0,0,0,0,0,0,0};
              }
#pragma unroll
              for (int nt = 0; nt < 4; ++nt)
                acc[mt][nt] = __builtin_amdgcn_mfma_f32_16x16x32_bf16(a1, bfr[1][nt], acc[mt][nt], 0, 0, 0);
            }
            // ks 2..7 contribute zero (WT rows >= 832 are 0): skipped
          }
        }
      } else {
        // ---- standard h-side path ----
        const u16* aptr = (w < 2) ? lo : hi;
        const int koff = (w & 1) * 256;
#pragma unroll
        for (int ks = 0; ks < 8; ++ks) {
#pragma unroll
          for (int mt = 0; mt < 4; ++mt) {
            s8v a = *(const s8v*)(aptr + (size_t)(mt * 16 + lm) * 512 + koff + ks * 32 + qk * 8);
#pragma unroll
            for (int nt = 0; nt < 4; ++nt)
              acc[mt][nt] = __builtin_amdgcn_mfma_f32_16x16x32_bf16(a, bfr[ks][nt], acc[mt][nt], 0, 0, 0);
          }
        }
      }

      // cross-wave K reduction: wave w keeps m-tile w, ships the other three
#pragma unroll
      for (int mt = 0; mt < 4; ++mt) {
        if (mt == w) continue;
        int slot = mt - (mt > w ? 1 : 0);
#pragma unroll
        for (int nt = 0; nt < 4; ++nt)
#pragma unroll
          for (int r = 0; r < 4; ++r)
            lpart[w][slot * 16 + qk * 4 + r][nt * 16 + lm] = acc[mt][nt][r];
      }
      __syncthreads();

      float z[4][4];
#pragma unroll
      for (int nt = 0; nt < 4; ++nt)
#pragma unroll
        for (int r = 0; r < 4; ++r) {
          float v = acc[w][nt][r];
#pragma unroll
          for (int ps = 0; ps < 4; ++ps) {
            if (ps == w) continue;
            int slot = w - (w > ps ? 1 : 0);
            v += lpart[ps][slot * 16 + qk * 4 + r][nt * 16 + lm];
          }
          z[nt][r] = v + bias4[nt];
        }

      // cell update: i,f,g,o = z[0..3]
      u16* hout = hbuf + ((size_t)(s & 1) * 6 + stage) * 64 * 512;
      u16* o3 = out3 + ((size_t)d * 256 + t) * 64 * 512;
#pragma unroll
      for (int r = 0; r < 4; ++r) {
        float zi = z[0][r], zf = z[1][r], zg = z[2][r], zo = z[3][r];
        float si = 1.f / (1.f + __expf(-zi));
        float sf = 1.f / (1.f + __expf(-zf));
        float so = 1.f / (1.f + __expf(-zo));
        float sg = zg / (1.f + fabsf(zg));
        float cn = sf * c[r] + si * sg;
        c[r] = cn;
        float h = so * (cn / (1.f + fabsf(cn)));
        u16 hb = f2b(h);
        size_t off = (size_t)(brow + r) * 512 + uu;
        hout[off] = hb;
        if (l == 2) o3[off] = hb;
      }
    }
    grid_bar(bar, (unsigned)NBLK * (unsigned)(s + 1));
  }
}

// ---------------------------------------------------------------------------
// Attention scores: per t-block, enc = 0.5*(out3[0][t]+out3[1][t]) on the fly,
// a = prelu(enc@Wa0+ba0), scores[b][t] = a@Wa1 + ba1.
// ---------------------------------------------------------------------------
__global__ __launch_bounds__(256) void attn_scores(
    const u16* __restrict__ out3, const u16* __restrict__ WaT,
    const float* __restrict__ ba0, const float* __restrict__ alpha_a,
    const float* __restrict__ Wa1, const float* __restrict__ ba1,
    float* __restrict__ scores)
{
  int t = blockIdx.x, tid = threadIdx.x;
  int w = tid >> 6, lane = tid & 63, lm = lane & 15, qk = lane >> 4;
  const u16* e0 = out3 + (size_t)t * 64 * 512;
  const u16* e1 = out3 + ((size_t)256 + t) * 64 * 512;
  const f4v fzero = {0.f, 0.f, 0.f, 0.f};
  f4v acc[16];
#pragma unroll
  for (int nt = 0; nt < 16; ++nt) acc[nt] = fzero;

  for (int ks = 0; ks < 16; ++ks) {
    size_t aoff = (size_t)(16 * w + lm) * 512 + ks * 32 + qk * 8;
    s8v a0 = *(const s8v*)(e0 + aoff);
    s8v a1 = *(const s8v*)(e1 + aoff);
    s8v af;
#pragma unroll
    for (int j = 0; j < 8; ++j)
      af[j] = (short)f2b(0.5f * (b2f((u16)a0[j]) + b2f((u16)a1[j])));
#pragma unroll
    for (int nt = 0; nt < 16; ++nt) {
      s8v bf = *(const s8v*)(WaT + (size_t)(nt * 16 + lm) * 512 + ks * 32 + qk * 8);
      acc[nt] = __builtin_amdgcn_mfma_f32_16x16x32_bf16(af, bf, acc[nt], 0, 0, 0);
    }
  }

  float sums[4] = {0.f, 0.f, 0.f, 0.f};
#pragma unroll
  for (int nt = 0; nt < 16; ++nt) {
    int col = nt * 16 + lm;
    float bb = ba0[col];
    float al = alpha_a[col];
    float wv = Wa1[col];
#pragma unroll
    for (int r = 0; r < 4; ++r) {
      float v = acc[nt][r] + bb;
      v = (v >= 0.f) ? v : al * v;
      sums[r] += v * wv;
    }
  }
  float bb1 = ba1[0];
#pragma unroll
  for (int r = 0; r < 4; ++r) {
    float v = sums[r];
    v += __shfl_xor(v, 1, 16);
    v += __shfl_xor(v, 2, 16);
    v += __shfl_xor(v, 4, 16);
    v += __shfl_xor(v, 8, 16);
    if (lm == 0) {
      int b = 16 * w + qk * 4 + r;
      scores[(size_t)b * 256 + t] = v + bb1;
    }
  }
}

// ---------------------------------------------------------------------------
// Softmax over T + pooled[b][u] = sum_t w[t]*enc[b][t][u]
// ---------------------------------------------------------------------------
__global__ __launch_bounds__(256) void attn_pool(
    const u16* __restrict__ out3, const float* __restrict__ scores,
    u16* __restrict__ pooled)
{
  __shared__ float red[256];
  __shared__ float wts[256];
  int b = blockIdx.x, tid = threadIdx.x;
  float s = scores[(size_t)b * 256 + tid];
  red[tid] = s; __syncthreads();
  for (int o = 128; o > 0; o >>= 1) { if (tid < o) red[tid] = fmaxf(red[tid], red[tid + o]); __syncthreads(); }
  float m = red[0]; __syncthreads();
  float e = __expf(s - m);
  red[tid] = e; __syncthreads();
  for (int o = 128; o > 0; o >>= 1) { if (tid < o) red[tid] += red[tid + o]; __syncthreads(); }
  float inv = 1.f / red[0];
  wts[tid] = e * inv; __syncthreads();

  int u2 = tid * 2;
  float a0 = 0.f, a1 = 0.f;
#pragma unroll 4
  for (int t = 0; t < 256; ++t) {
    float wt = wts[t];
    const ushort2 v0 = *(const ushort2*)(out3 + ((size_t)t * 64 + b) * 512 + u2);
    const ushort2 v1 = *(const ushort2*)(out3 + (((size_t)256 + t) * 64 + b) * 512 + u2);
    a0 += wt * 0.5f * (b2f(v0.x) + b2f(v1.x));
    a1 += wt * 0.5f * (b2f(v0.y) + b2f(v1.y));
  }
  pooled[(size_t)b * 512 + u2] = f2b(a0);
  pooled[(size_t)b * 512 + u2 + 1] = f2b(a1);
}

// ---------------------------------------------------------------------------
// Head: h = prelu(BN(pooled@Wd0+bd0)); out = softmax(h@Wd1+bd1)  (float out)
// ---------------------------------------------------------------------------
__global__ __launch_bounds__(256) void head(
    const u16* __restrict__ pooled, const u16* __restrict__ WdT,
    const float* __restrict__ bd0, const float* __restrict__ gamma,
    const float* __restrict__ beta, const float* __restrict__ bn_mean,
    const float* __restrict__ bn_var, const float* __restrict__ alpha_h,
    const float* __restrict__ Wd1, const float* __restrict__ bd1,
    float* __restrict__ outp)
{
  __shared__ float hl[64][260];
  __shared__ float lg[64][8];
  int tid = threadIdx.x;
  int w = tid >> 6, lane = tid & 63, lm = lane & 15, qk = lane >> 4;
  const f4v fzero = {0.f, 0.f, 0.f, 0.f};
  f4v acc[16];
#pragma unroll
  for (int nt = 0; nt < 16; ++nt) acc[nt] = fzero;
  for (int ks = 0; ks < 16; ++ks) {
    s8v a = *(const s8v*)(pooled + (size_t)(16 * w + lm) * 512 + ks * 32 + qk * 8);
#pragma unroll
    for (int nt = 0; nt < 16; ++nt) {
      s8v bf = *(const s8v*)(WdT + (size_t)(nt * 16 + lm) * 512 + ks * 32 + qk * 8);
      acc[nt] = __builtin_amdgcn_mfma_f32_16x16x32_bf16(a, bf, acc[nt], 0, 0, 0);
    }
  }
#pragma unroll
  for (int nt = 0; nt < 16; ++nt) {
    int col = nt * 16 + lm;
    float mn = bn_mean[col];
    float sc = gamma[col] * rsqrtf(bn_var[col] + 1e-3f);
    float be = beta[col];
    float al = alpha_h[col];
    float b0 = bd0[col];
#pragma unroll
    for (int r = 0; r < 4; ++r) {
      float v = acc[nt][r] + b0;
      v = (v - mn) * sc + be;
      v = (v >= 0.f) ? v : al * v;
      hl[16 * w + qk * 4 + r][col] = v;
    }
  }
  __syncthreads();
  for (int idx = tid; idx < 448; idx += 256) {
    int b = idx / 7, cc = idx - b * 7;
    float sv = bd1[cc];
    for (int k = 0; k < 256; ++k) sv += hl[b][k] * Wd1[k * 7 + cc];
    lg[b][cc] = sv;
  }
  __syncthreads();
  if (tid < 64) {
    float mx = -1e30f;
#pragma unroll
    for (int cc = 0; cc < 7; ++cc) mx = fmaxf(mx, lg[tid][cc]);
    float sum = 0.f; float ex[7];
#pragma unroll
    for (int cc = 0; cc < 7; ++cc) { ex[cc] = __expf(lg[tid][cc] - mx); sum += ex[cc]; }
    float inv = 1.f / sum;
#pragma unroll
    for (int cc = 0; cc < 7; ++cc) outp[tid * 7 + cc] = ex[cc] * inv;
  }
}

// ---------------------------------------------------------------------------
extern "C" void kernel_launch(void* const* d_in, const int* in_sizes, int n_in,
                              void* d_out, int out_size, void* d_ws, size_t ws_size,
                              hipStream_t stream)
{
  (void)in_sizes; (void)n_in; (void)out_size; (void)ws_size;
  const int*   ids     = (const int*)d_in[0];
  const float* emb     = (const float*)d_in[1];
  const float* k0      = (const float*)d_in[2];
  const float* k12     = (const float*)d_in[3];
  const float* rec     = (const float*)d_in[4];
  const float* bias    = (const float*)d_in[5];
  const float* Wa0     = (const float*)d_in[6];
  const float* ba0     = (const float*)d_in[7];
  const float* alpha_a = (const float*)d_in[8];
  const float* Wa1     = (const float*)d_in[9];
  const float* ba1     = (const float*)d_in[10];
  const float* Wd0     = (const float*)d_in[11];
  const float* bd0     = (const float*)d_in[12];
  const float* gamma   = (const float*)d_in[13];
  const float* beta    = (const float*)d_in[14];
  const float* bn_mean = (const float*)d_in[15];
  const float* bn_var  = (const float*)d_in[16];
  const float* alpha_h = (const float*)d_in[17];
  const float* Wd1     = (const float*)d_in[18];
  const float* bd1     = (const float*)d_in[19];

  char* ws = (char*)d_ws;
  u16* WT      = (u16*)(ws);                    // 6*2048*1024*2   = 25,165,824
  u16* hbuf    = (u16*)(ws + 25165824);         // 2*6*64*512*2    =    786,432
  u16* out3    = (u16*)(ws + 25952256);         // 2*256*64*512*2  = 33,554,432
  u16* WaT     = (u16*)(ws + 59506688);         //                 =    262,144
  u16* WdT     = (u16*)(ws + 59768832);         //                 =    262,144
  float* scores= (float*)(ws + 60030976);       // 64*256*4        =     65,536
  u16* pooled  = (u16*)(ws + 60096512);         // 64*512*2        =     65,536
  unsigned* bar= (unsigned*)(ws + 60162048);    // 64 B barrier counter
                                                // total             60,162,112 B

  hipMemsetAsync(hbuf, 0, 786432, stream);
  hipMemsetAsync(bar, 0, 64, stream);

  prep_weights<<<dim3(3136), dim3(256), 0, stream>>>(k0, k12, rec, Wa0, Wd0, WT, WaT, WdT);

  void* args[] = { (void*)&WT, (void*)&emb, (void*)&ids, (void*)&bias,
                   (void*)&hbuf, (void*)&out3, (void*)&bar };
  hipLaunchCooperativeKernel((void*)lstm_main, dim3(NBLK), dim3(256), args, 0, stream);

  attn_scores<<<dim3(256), dim3(256), 0, stream>>>(out3, WaT, ba0, alpha_a, Wa1, ba1, scores);
  attn_pool<<<dim3(64), dim3(256), 0, stream>>>(out3, scores, pooled);
  head<<<dim3(1), dim3(256), 0, stream>>>(pooled, WdT, bd0, gamma, beta, bn_mean, bn_var,
                                          alpha_h, Wd1, bd1, (float*)d_out);
}

// Round 5
// 5753.407 us; speedup vs baseline: 1.8109x; 1.3250x over previous
//
#include <hip/hip_runtime.h>
#include <hip/hip_bf16.h>

typedef short s8v __attribute__((ext_vector_type(8)));   // 8 bf16 (4 VGPRs) MFMA frag
typedef float f4v __attribute__((ext_vector_type(4)));   // MFMA accum frag / float4 load

#define NBLK 192   // 6 stages * 32 blocks
#define HDEPTH 32  // h-history ring depth (address reuse distance)

typedef unsigned short u16;

__device__ __forceinline__ float b2f(u16 u) {
  union { unsigned int i; float f; } v; v.i = ((unsigned int)u) << 16; return v.f;
}
__device__ __forceinline__ u16 f2b(float f) {
  union { float f; unsigned int i; } v; v.f = f;
  unsigned int x = v.i;
  return (u16)((x + 0x7fffu + ((x >> 16) & 1u)) >> 16);  // RNE
}
__device__ __forceinline__ s8v cvt8(f4v a, f4v b) {
  s8v r;
  r[0] = (short)f2b(a[0]); r[1] = (short)f2b(a[1]);
  r[2] = (short)f2b(a[2]); r[3] = (short)f2b(a[3]);
  r[4] = (short)f2b(b[0]); r[5] = (short)f2b(b[1]);
  r[6] = (short)f2b(b[2]); r[7] = (short)f2b(b[3]);
  return r;
}

// ---------------------------------------------------------------------------
// Grid barrier WITHOUT per-step cache maintenance.  Data correctness comes
// from: (a) h stores are write-through (system-scope atomic stores) so
// nothing shared is dirty in L2; (b) __syncthreads drains each wave's vmcnt
// before s_barrier, so all h stores are at the coherence point before the
// arrive; (c) h addresses rotate through a 32-deep ring and an acquire fence
// every 8th step bounds cached-copy age to 8 < 32 -> no stale hits.
// ---------------------------------------------------------------------------
__device__ __forceinline__ void grid_bar(unsigned* cnt, unsigned target, bool inv) {
  __syncthreads();                      // each wave: s_waitcnt vmcnt(0) + s_barrier
  if (threadIdx.x == 0) {
    asm volatile("" ::: "memory");
    __builtin_amdgcn_s_waitcnt(0);      // belt & braces for wave 0
    __hip_atomic_fetch_add(cnt, 1u, __ATOMIC_RELAXED, __HIP_MEMORY_SCOPE_AGENT);
    while (__hip_atomic_load(cnt, __ATOMIC_RELAXED, __HIP_MEMORY_SCOPE_AGENT) < target)
      __builtin_amdgcn_s_sleep(1);
    if (inv)
      __builtin_amdgcn_fence(__ATOMIC_ACQUIRE, "agent");  // periodic L1/L2 inv
  }
  __syncthreads();
}

// ---------------------------------------------------------------------------
// P1: build transposed bf16 weights from float32 sources.
// WT[stage][col 0..2047][k 0..1023] (bf16), stage = d*3+l:
//   l==0 : k<512 -> rec[d][0][k][col];  k-512 in [0,300) -> k0[d][k-512][col]; else 0
//   l>=1 : k<512 -> k12[d][l-1][k][col]; else rec[d][l][k-512][col]
// WaT[n][k] = Wa0[k][n];  WdT likewise for Wd0.
// ---------------------------------------------------------------------------
__global__ __launch_bounds__(256) void prep_weights(
    const float* __restrict__ k0, const float* __restrict__ k12,
    const float* __restrict__ rec, const float* __restrict__ Wa0,
    const float* __restrict__ Wd0,
    u16* __restrict__ WT, u16* __restrict__ WaT, u16* __restrict__ WdT)
{
  __shared__ u16 tl[64][65];
  int bid = blockIdx.x, tid = threadIdx.x;
  if (bid < 3072) {
    int stage = bid >> 9;
    int t2 = bid & 511;
    int ct = t2 >> 4, kt = t2 & 15;
    int d = stage / 3, l = stage - 3 * d;
    int colbase = ct * 64, kbase = kt * 64;
    int cl = tid & 63;
#pragma unroll
    for (int i = 0; i < 16; ++i) {
      int kl = i * 4 + (tid >> 6);
      int k = kbase + kl, col = colbase + cl;
      float v;
      if (l == 0) {
        if (k < 512) v = rec[((size_t)(d * 3 + 0) * 512 + k) * 2048 + col];
        else { int j = k - 512; v = (j < 300) ? k0[((size_t)d * 300 + j) * 2048 + col] : 0.f; }
      } else {
        if (k < 512) v = k12[((size_t)(d * 2 + (l - 1)) * 512 + k) * 2048 + col];
        else         v = rec[((size_t)(d * 3 + l) * 512 + (k - 512)) * 2048 + col];
      }
      tl[kl][cl] = f2b(v);
    }
    __syncthreads();
#pragma unroll
    for (int i = 0; i < 16; ++i) {
      int cl2 = i * 4 + (tid >> 6);
      int kl2 = tid & 63;
      WT[((size_t)stage * 2048 + colbase + cl2) * 1024 + kbase + kl2] = tl[kl2][cl2];
    }
  } else {
    int m = bid - 3072;
    int mat = m >> 5, tt = m & 31;
    int nt = tt & 3, kt = tt >> 2;
    const float* src = mat ? Wd0 : Wa0;
    u16* dst = mat ? WdT : WaT;
    int nbase = nt * 64, kbase = kt * 64;
    int cl = tid & 63;
#pragma unroll
    for (int i = 0; i < 16; ++i) {
      int kl = i * 4 + (tid >> 6);
      tl[kl][cl] = f2b(src[(size_t)(kbase + kl) * 256 + nbase + cl]);
    }
    __syncthreads();
#pragma unroll
    for (int i = 0; i < 16; ++i) {
      int nl = i * 4 + (tid >> 6);
      int kl = tid & 63;
      dst[(size_t)(nbase + nl) * 512 + kbase + kl] = tl[kl][nl];
    }
  }
}

// ---------------------------------------------------------------------------
// Main persistent LSTM kernel.  192 blocks: stage = bid>>5 (d*3+l), slice = bid&31.
// Block owns units [u0,u0+16).  Step s, layer l processes t = s-l.
// h lives in hist[t & 31][stage][64][512] (write-through stores, cached loads).
// out3 ALIASES WT (WT is dead after the pre-loop barrier).
// ---------------------------------------------------------------------------
__global__ __launch_bounds__(256, 1) void lstm_main(
    const u16* __restrict__ WT, const float* __restrict__ emb,
    const int* __restrict__ ids, const float* __restrict__ bias,
    u16* __restrict__ hist, const u16* __restrict__ zbuf,
    u16* __restrict__ out3, unsigned* __restrict__ bar)
{
  __shared__ float lpart[4][48][68];   // [src wave][3 m-tiles *16][64 cols+pad]
  const int tid = threadIdx.x;
  const int w = tid >> 6;            // wave id (K-split, and cell-update row group)
  const int lane = tid & 63;
  const int lm = lane & 15, qk = lane >> 4;
  const int bid = blockIdx.x;
  const int stage = bid >> 5;
  const int slice = bid & 31;
  const int u0 = slice * 16;
  const int d = stage / 3, l = stage - 3 * d;

  // B fragments: col = nt*512 + u0 + lm (gate nt), k = w*256 + ks*32 + qk*8
  s8v bfr[8][4];
#pragma unroll
  for (int ks = 0; ks < 8; ++ks)
#pragma unroll
    for (int nt = 0; nt < 4; ++nt)
      bfr[ks][nt] = *(const s8v*)(WT + ((size_t)stage * 2048 + nt * 512 + u0 + lm) * 1024
                                  + w * 256 + ks * 32 + qk * 8);
  float bias4[4];
#pragma unroll
  for (int nt = 0; nt < 4; ++nt)
    bias4[nt] = bias[((size_t)d * 3 + l) * 2048 + nt * 512 + u0 + lm];

  float c[4] = {0.f, 0.f, 0.f, 0.f};      // cell state, rows 16w+qk*4+r, unit u0+lm
  const int brow = 16 * w + qk * 4;
  const int uu = u0 + lm;
  const f4v fzero = {0.f, 0.f, 0.f, 0.f};

  // All B-frag reads must complete before any out3 store tramples WT.
  grid_bar(bar, (unsigned)NBLK, false);

  for (int s = 0; s < 258; ++s) {
    int t = s - l;
    if (t >= 0 && t < 256) {
      int tx = d ? (255 - t) : t;        // time index into input sequence
      const u16* lo;
      const u16* hi;
      if (l == 0) {
        lo = (t == 0) ? zbuf
             : hist + ((size_t)((t - 1) & (HDEPTH - 1)) * 6 + stage) * 64 * 512;  // h1[t-1]
        hi = lo;                                                  // unused (emb path)
      } else {
        lo = hist + ((size_t)(t & (HDEPTH - 1)) * 6 + (stage - 1)) * 64 * 512;    // h_{l-1}[t]
        hi = (t == 0) ? zbuf
             : hist + ((size_t)((t - 1) & (HDEPTH - 1)) * 6 + stage) * 64 * 512;  // h_l[t-1]
      }

      f4v acc[4][4];
#pragma unroll
      for (int mt = 0; mt < 4; ++mt)
#pragma unroll
        for (int nt = 0; nt < 4; ++nt) acc[mt][nt] = fzero;

      if (l == 0 && w >= 2) {
        // ---- input-projection side: A = emb[ids[row][tx]] (float row, 16B aligned:
        //      row byte offset = id*1200, 1200 = 75*16) ----
        if (w == 2) {                    // j in [0,256): all fragments fully valid
#pragma unroll
          for (int mt = 0; mt < 4; ++mt) {
            const int id = ids[(mt * 16 + lm) * 256 + tx];
            const float* er = emb + (size_t)id * 300;
#pragma unroll
            for (int ks = 0; ks < 8; ++ks) {
              f4v f0 = *(const f4v*)(er + ks * 32 + qk * 8);
              f4v f1 = *(const f4v*)(er + ks * 32 + qk * 8 + 4);
              s8v a = cvt8(f0, f1);
#pragma unroll
              for (int nt = 0; nt < 4; ++nt)
                acc[mt][nt] = __builtin_amdgcn_mfma_f32_16x16x32_bf16(a, bfr[ks][nt], acc[mt][nt], 0, 0, 0);
            }
          }
        } else {                         // w==3: j in [256,512); only ks 0,1 nonzero
#pragma unroll
          for (int mt = 0; mt < 4; ++mt) {
            const int id = ids[(mt * 16 + lm) * 256 + tx];
            const float* er = emb + (size_t)id * 300;
            {                            // ks=0: j 256..287 all valid
              f4v f0 = *(const f4v*)(er + 256 + qk * 8);
              f4v f1 = *(const f4v*)(er + 256 + qk * 8 + 4);
              s8v a0 = cvt8(f0, f1);
#pragma unroll
              for (int nt = 0; nt < 4; ++nt)
                acc[mt][nt] = __builtin_amdgcn_mfma_f32_16x16x32_bf16(a0, bfr[0][nt], acc[mt][nt], 0, 0, 0);
            }
            {                            // ks=1: j 288..319; valid only j<300
              s8v a1;
              if (qk == 0) {             // j 288..295
                f4v f0 = *(const f4v*)(er + 288);
                f4v f1 = *(const f4v*)(er + 292);
                a1 = cvt8(f0, f1);
              } else if (qk == 1) {      // j 296..303: 296..299 valid, rest zero
                f4v f0 = *(const f4v*)(er + 296);
                a1 = cvt8(f0, fzero);
              } else {                   // j >= 304: WT rows are zero anyway
                a1 = (s8v){0,0,0,0,0,0,0,0};
              }
#pragma unroll
              for (int nt = 0; nt < 4; ++nt)
                acc[mt][nt] = __builtin_amdgcn_mfma_f32_16x16x32_bf16(a1, bfr[1][nt], acc[mt][nt], 0, 0, 0);
            }
            // ks 2..7 contribute zero (WT rows >= 832 are 0): skipped
          }
        }
      } else {
        // ---- standard h-side path (plain cached loads; addresses are fresh) ----
        const u16* aptr = (w < 2) ? lo : hi;
        const int koff = (w & 1) * 256;
#pragma unroll
        for (int ks = 0; ks < 8; ++ks) {
#pragma unroll
          for (int mt = 0; mt < 4; ++mt) {
            s8v a = *(const s8v*)(aptr + (size_t)(mt * 16 + lm) * 512 + koff + ks * 32 + qk * 8);
#pragma unroll
            for (int nt = 0; nt < 4; ++nt)
              acc[mt][nt] = __builtin_amdgcn_mfma_f32_16x16x32_bf16(a, bfr[ks][nt], acc[mt][nt], 0, 0, 0);
          }
        }
      }

      // cross-wave K reduction: wave w keeps m-tile w, ships the other three
#pragma unroll
      for (int mt = 0; mt < 4; ++mt) {
        if (mt == w) continue;
        int slot = mt - (mt > w ? 1 : 0);
#pragma unroll
        for (int nt = 0; nt < 4; ++nt)
#pragma unroll
          for (int r = 0; r < 4; ++r)
            lpart[w][slot * 16 + qk * 4 + r][nt * 16 + lm] = acc[mt][nt][r];
      }
      __syncthreads();

      float z[4][4];
#pragma unroll
      for (int nt = 0; nt < 4; ++nt)
#pragma unroll
        for (int r = 0; r < 4; ++r) {
          float v = acc[w][nt][r];
#pragma unroll
          for (int ps = 0; ps < 4; ++ps) {
            if (ps == w) continue;
            int slot = w - (w > ps ? 1 : 0);
            v += lpart[ps][slot * 16 + qk * 4 + r][nt * 16 + lm];
          }
          z[nt][r] = v + bias4[nt];
        }

      // cell update: i,f,g,o = z[0..3]
      u16* hq = hist + ((size_t)(t & (HDEPTH - 1)) * 6 + stage) * 64 * 512;
      u16* o3 = out3 + ((size_t)d * 256 + t) * 64 * 512;
#pragma unroll
      for (int r = 0; r < 4; ++r) {
        float zi = z[0][r], zf = z[1][r], zg = z[2][r], zo = z[3][r];
        float si = 1.f / (1.f + __expf(-zi));
        float sf = 1.f / (1.f + __expf(-zf));
        float so = 1.f / (1.f + __expf(-zo));
        float sg = zg / (1.f + fabsf(zg));
        float cn = sf * c[r] + si * sg;
        c[r] = cn;
        float h = so * (cn / (1.f + fabsf(cn)));
        u16 hb = f2b(h);
        size_t off = (size_t)(brow + r) * 512 + uu;
        // write-through to coherence point (never dirty in L2)
        __hip_atomic_store(hq + off, hb, __ATOMIC_RELAXED, __HIP_MEMORY_SCOPE_SYSTEM);
        if (l == 2) o3[off] = hb;   // plain cached store (read only after kernel end)
      }
    }
    grid_bar(bar, (unsigned)NBLK * (unsigned)(s + 2), (s & 7) == 7);
  }
}

// ---------------------------------------------------------------------------
// Attention scores: per t-block, enc = 0.5*(out3[0][t]+out3[1][t]) on the fly,
// a = prelu(enc@Wa0+ba0), scores[b][t] = a@Wa1 + ba1.
// ---------------------------------------------------------------------------
__global__ __launch_bounds__(256) void attn_scores(
    const u16* __restrict__ out3, const u16* __restrict__ WaT,
    const float* __restrict__ ba0, const float* __restrict__ alpha_a,
    const float* __restrict__ Wa1, const float* __restrict__ ba1,
    float* __restrict__ scores)
{
  int t = blockIdx.x, tid = threadIdx.x;
  int w = tid >> 6, lane = tid & 63, lm = lane & 15, qk = lane >> 4;
  const u16* e0 = out3 + (size_t)t * 64 * 512;
  const u16* e1 = out3 + ((size_t)256 + t) * 64 * 512;
  const f4v fzero = {0.f, 0.f, 0.f, 0.f};
  f4v acc[16];
#pragma unroll
  for (int nt = 0; nt < 16; ++nt) acc[nt] = fzero;

  for (int ks = 0; ks < 16; ++ks) {
    size_t aoff = (size_t)(16 * w + lm) * 512 + ks * 32 + qk * 8;
    s8v a0 = *(const s8v*)(e0 + aoff);
    s8v a1 = *(const s8v*)(e1 + aoff);
    s8v af;
#pragma unroll
    for (int j = 0; j < 8; ++j)
      af[j] = (short)f2b(0.5f * (b2f((u16)a0[j]) + b2f((u16)a1[j])));
#pragma unroll
    for (int nt = 0; nt < 16; ++nt) {
      s8v bf = *(const s8v*)(WaT + (size_t)(nt * 16 + lm) * 512 + ks * 32 + qk * 8);
      acc[nt] = __builtin_amdgcn_mfma_f32_16x16x32_bf16(af, bf, acc[nt], 0, 0, 0);
    }
  }

  float sums[4] = {0.f, 0.f, 0.f, 0.f};
#pragma unroll
  for (int nt = 0; nt < 16; ++nt) {
    int col = nt * 16 + lm;
    float bb = ba0[col];
    float al = alpha_a[col];
    float wv = Wa1[col];
#pragma unroll
    for (int r = 0; r < 4; ++r) {
      float v = acc[nt][r] + bb;
      v = (v >= 0.f) ? v : al * v;
      sums[r] += v * wv;
    }
  }
  float bb1 = ba1[0];
#pragma unroll
  for (int r = 0; r < 4; ++r) {
    float v = sums[r];
    v += __shfl_xor(v, 1, 16);
    v += __shfl_xor(v, 2, 16);
    v += __shfl_xor(v, 4, 16);
    v += __shfl_xor(v, 8, 16);
    if (lm == 0) {
      int b = 16 * w + qk * 4 + r;
      scores[(size_t)b * 256 + t] = v + bb1;
    }
  }
}

// ---------------------------------------------------------------------------
// Softmax over T + pooled[b][u] = sum_t w[t]*enc[b][t][u]
// ---------------------------------------------------------------------------
__global__ __launch_bounds__(256) void attn_pool(
    const u16* __restrict__ out3, const float* __restrict__ scores,
    u16* __restrict__ pooled)
{
  __shared__ float red[256];
  __shared__ float wts[256];
  int b = blockIdx.x, tid = threadIdx.x;
  float s = scores[(size_t)b * 256 + tid];
  red[tid] = s; __syncthreads();
  for (int o = 128; o > 0; o >>= 1) { if (tid < o) red[tid] = fmaxf(red[tid], red[tid + o]); __syncthreads(); }
  float m = red[0]; __syncthreads();
  float e = __expf(s - m);
  red[tid] = e; __syncthreads();
  for (int o = 128; o > 0; o >>= 1) { if (tid < o) red[tid] += red[tid + o]; __syncthreads(); }
  float inv = 1.f / red[0];
  wts[tid] = e * inv; __syncthreads();

  int u2 = tid * 2;
  float a0 = 0.f, a1 = 0.f;
#pragma unroll 4
  for (int t = 0; t < 256; ++t) {
    float wt = wts[t];
    const ushort2 v0 = *(const ushort2*)(out3 + ((size_t)t * 64 + b) * 512 + u2);
    const ushort2 v1 = *(const ushort2*)(out3 + (((size_t)256 + t) * 64 + b) * 512 + u2);
    a0 += wt * 0.5f * (b2f(v0.x) + b2f(v1.x));
    a1 += wt * 0.5f * (b2f(v0.y) + b2f(v1.y));
  }
  pooled[(size_t)b * 512 + u2] = f2b(a0);
  pooled[(size_t)b * 512 + u2 + 1] = f2b(a1);
}

// ---------------------------------------------------------------------------
// Head: h = prelu(BN(pooled@Wd0+bd0)); out = softmax(h@Wd1+bd1)  (float out)
// ---------------------------------------------------------------------------
__global__ __launch_bounds__(256) void head(
    const u16* __restrict__ pooled, const u16* __restrict__ WdT,
    const float* __restrict__ bd0, const float* __restrict__ gamma,
    const float* __restrict__ beta, const float* __restrict__ bn_mean,
    const float* __restrict__ bn_var, const float* __restrict__ alpha_h,
    const float* __restrict__ Wd1, const float* __restrict__ bd1,
    float* __restrict__ outp)
{
  __shared__ float hl[64][260];
  __shared__ float lg[64][8];
  int tid = threadIdx.x;
  int w = tid >> 6, lane = tid & 63, lm = lane & 15, qk = lane >> 4;
  const f4v fzero = {0.f, 0.f, 0.f, 0.f};
  f4v acc[16];
#pragma unroll
  for (int nt = 0; nt < 16; ++nt) acc[nt] = fzero;
  for (int ks = 0; ks < 16; ++ks) {
    s8v a = *(const s8v*)(pooled + (size_t)(16 * w + lm) * 512 + ks * 32 + qk * 8);
#pragma unroll
    for (int nt = 0; nt < 16; ++nt) {
      s8v bf = *(const s8v*)(WdT + (size_t)(nt * 16 + lm) * 512 + ks * 32 + qk * 8);
      acc[nt] = __builtin_amdgcn_mfma_f32_16x16x32_bf16(a, bf, acc[nt], 0, 0, 0);
    }
  }
#pragma unroll
  for (int nt = 0; nt < 16; ++nt) {
    int col = nt * 16 + lm;
    float mn = bn_mean[col];
    float sc = gamma[col] * rsqrtf(bn_var[col] + 1e-3f);
    float be = beta[col];
    float al = alpha_h[col];
    float b0 = bd0[col];
#pragma unroll
    for (int r = 0; r < 4; ++r) {
      float v = acc[nt][r] + b0;
      v = (v - mn) * sc + be;
      v = (v >= 0.f) ? v : al * v;
      hl[16 * w + qk * 4 + r][col] = v;
    }
  }
  __syncthreads();
  for (int idx = tid; idx < 448; idx += 256) {
    int b = idx / 7, cc = idx - b * 7;
    float sv = bd1[cc];
    for (int k = 0; k < 256; ++k) sv += hl[b][k] * Wd1[k * 7 + cc];
    lg[b][cc] = sv;
  }
  __syncthreads();
  if (tid < 64) {
    float mx = -1e30f;
#pragma unroll
    for (int cc = 0; cc < 7; ++cc) mx = fmaxf(mx, lg[tid][cc]);
    float sum = 0.f; float ex[7];
#pragma unroll
    for (int cc = 0; cc < 7; ++cc) { ex[cc] = __expf(lg[tid][cc] - mx); sum += ex[cc]; }
    float inv = 1.f / sum;
#pragma unroll
    for (int cc = 0; cc < 7; ++cc) outp[tid * 7 + cc] = ex[cc] * inv;
  }
}

// ---------------------------------------------------------------------------
extern "C" void kernel_launch(void* const* d_in, const int* in_sizes, int n_in,
                              void* d_out, int out_size, void* d_ws, size_t ws_size,
                              hipStream_t stream)
{
  (void)in_sizes; (void)n_in; (void)out_size; (void)ws_size;
  const int*   ids     = (const int*)d_in[0];
  const float* emb     = (const float*)d_in[1];
  const float* k0      = (const float*)d_in[2];
  const float* k12     = (const float*)d_in[3];
  const float* rec     = (const float*)d_in[4];
  const float* bias    = (const float*)d_in[5];
  const float* Wa0     = (const float*)d_in[6];
  const float* ba0     = (const float*)d_in[7];
  const float* alpha_a = (const float*)d_in[8];
  const float* Wa1     = (const float*)d_in[9];
  const float* ba1     = (const float*)d_in[10];
  const float* Wd0     = (const float*)d_in[11];
  const float* bd0     = (const float*)d_in[12];
  const float* gamma   = (const float*)d_in[13];
  const float* beta    = (const float*)d_in[14];
  const float* bn_mean = (const float*)d_in[15];
  const float* bn_var  = (const float*)d_in[16];
  const float* alpha_h = (const float*)d_in[17];
  const float* Wd1     = (const float*)d_in[18];
  const float* bd1     = (const float*)d_in[19];

  char* ws = (char*)d_ws;
  // out3 (33,554,432 B) ALIASES WT (25,165,824 B): WT is dead once lstm_main's
  // pre-loop barrier passes (B-frags register-resident); out3 writes start after.
  u16* WT      = (u16*)(ws);                    // [0, 25.17 MB)
  u16* out3    = (u16*)(ws);                    // [0, 33.55 MB)
  u16* hist    = (u16*)(ws + 33554432);         // 32*6*64*512*2 = 12,582,912
  u16* WaT     = (u16*)(ws + 46137344);         // 262,144
  u16* WdT     = (u16*)(ws + 46399488);         // 262,144
  float* scores= (float*)(ws + 46661632);       // 65,536
  u16* pooled  = (u16*)(ws + 46727168);         // 65,536
  u16* zbuf    = (u16*)(ws + 46792704);         // 65,536 (zero tile)
  unsigned* bar= (unsigned*)(ws + 46858240);    // 128 B barrier counter
                                                // total 46,858,368 B

  hipMemsetAsync(zbuf, 0, 65536, stream);
  hipMemsetAsync(bar, 0, 128, stream);

  prep_weights<<<dim3(3136), dim3(256), 0, stream>>>(k0, k12, rec, Wa0, Wd0, WT, WaT, WdT);

  void* args[] = { (void*)&WT, (void*)&emb, (void*)&ids, (void*)&bias,
                   (void*)&hist, (void*)&zbuf, (void*)&out3, (void*)&bar };
  hipLaunchCooperativeKernel((void*)lstm_main, dim3(NBLK), dim3(256), args, 0, stream);

  attn_scores<<<dim3(256), dim3(256), 0, stream>>>(out3, WaT, ba0, alpha_a, Wa1, ba1, scores);
  attn_pool<<<dim3(64), dim3(256), 0, stream>>>(out3, scores, pooled);
  head<<<dim3(1), dim3(256), 0, stream>>>(pooled, WdT, bd0, gamma, beta, bn_mean, bn_var,
                                          alpha_h, Wd1, bd1, (float*)d_out);
}

// Round 6
// 5496.716 us; speedup vs baseline: 1.8954x; 1.0467x over previous
//
#include <hip/hip_runtime.h>
#include <hip/hip_bf16.h>

typedef short s8v __attribute__((ext_vector_type(8)));   // 8 bf16 (4 VGPRs) MFMA frag
typedef float f4v __attribute__((ext_vector_type(4)));   // MFMA accum frag / float4 load

#define NBLK 192   // 6 stages * 32 blocks
#define HDEPTH 32  // h-history ring depth (address reuse distance)

typedef unsigned short u16;
typedef unsigned long long u64;

__device__ __forceinline__ float b2f(u16 u) {
  union { unsigned int i; float f; } v; v.i = ((unsigned int)u) << 16; return v.f;
}
__device__ __forceinline__ u16 f2b(float f) {
  union { float f; unsigned int i; } v; v.f = f;
  unsigned int x = v.i;
  return (u16)((x + 0x7fffu + ((x >> 16) & 1u)) >> 16);  // RNE
}
__device__ __forceinline__ s8v cvt8(f4v a, f4v b) {
  s8v r;
  r[0] = (short)f2b(a[0]); r[1] = (short)f2b(a[1]);
  r[2] = (short)f2b(a[2]); r[3] = (short)f2b(a[3]);
  r[4] = (short)f2b(b[0]); r[5] = (short)f2b(b[1]);
  r[6] = (short)f2b(b[2]); r[7] = (short)f2b(b[3]);
  return r;
}

// ---------------------------------------------------------------------------
// P1: build transposed bf16 weights from float32 sources.
// WT[stage][col 0..2047][k 0..1023] (bf16), stage = d*3+l:
//   l==0 : k<512 -> rec[d][0][k][col];  k-512 in [0,300) -> k0[d][k-512][col]; else 0
//   l>=1 : k<512 -> k12[d][l-1][k][col]; else rec[d][l][k-512][col]
// WaT[n][k] = Wa0[k][n];  WdT likewise for Wd0.
// ---------------------------------------------------------------------------
__global__ __launch_bounds__(256) void prep_weights(
    const float* __restrict__ k0, const float* __restrict__ k12,
    const float* __restrict__ rec, const float* __restrict__ Wa0,
    const float* __restrict__ Wd0,
    u16* __restrict__ WT, u16* __restrict__ WaT, u16* __restrict__ WdT)
{
  __shared__ u16 tl[64][65];
  int bid = blockIdx.x, tid = threadIdx.x;
  if (bid < 3072) {
    int stage = bid >> 9;
    int t2 = bid & 511;
    int ct = t2 >> 4, kt = t2 & 15;
    int d = stage / 3, l = stage - 3 * d;
    int colbase = ct * 64, kbase = kt * 64;
    int cl = tid & 63;
#pragma unroll
    for (int i = 0; i < 16; ++i) {
      int kl = i * 4 + (tid >> 6);
      int k = kbase + kl, col = colbase + cl;
      float v;
      if (l == 0) {
        if (k < 512) v = rec[((size_t)(d * 3 + 0) * 512 + k) * 2048 + col];
        else { int j = k - 512; v = (j < 300) ? k0[((size_t)d * 300 + j) * 2048 + col] : 0.f; }
      } else {
        if (k < 512) v = k12[((size_t)(d * 2 + (l - 1)) * 512 + k) * 2048 + col];
        else         v = rec[((size_t)(d * 3 + l) * 512 + (k - 512)) * 2048 + col];
      }
      tl[kl][cl] = f2b(v);
    }
    __syncthreads();
#pragma unroll
    for (int i = 0; i < 16; ++i) {
      int cl2 = i * 4 + (tid >> 6);
      int kl2 = tid & 63;
      WT[((size_t)stage * 2048 + colbase + cl2) * 1024 + kbase + kl2] = tl[kl2][cl2];
    }
  } else {
    int m = bid - 3072;
    int mat = m >> 5, tt = m & 31;
    int nt = tt & 3, kt = tt >> 2;
    const float* src = mat ? Wd0 : Wa0;
    u16* dst = mat ? WdT : WaT;
    int nbase = nt * 64, kbase = kt * 64;
    int cl = tid & 63;
#pragma unroll
    for (int i = 0; i < 16; ++i) {
      int kl = i * 4 + (tid >> 6);
      tl[kl][cl] = f2b(src[(size_t)(kbase + kl) * 256 + nbase + cl]);
    }
    __syncthreads();
#pragma unroll
    for (int i = 0; i < 16; ++i) {
      int nl = i * 4 + (tid >> 6);
      int kl = tid & 63;
      dst[(size_t)(nbase + nl) * 512 + kbase + kl] = tl[kl][nl];
    }
  }
}

// ---------------------------------------------------------------------------
// Main persistent LSTM kernel.  192 blocks: stage = bid>>5 (d*3+l), slice = bid&31.
// Dependency-flag pipeline sync (NO global barrier):
//   flags[stage*32+slice] = completed_step+1 (4B system-scope store, no RMW).
//   At step s a block waits: own stage >= s, producer stage (l-1) >= s,
//   consumer stage (l+1) >= s-24 (WAR backpressure for the 32-deep h ring).
// h: LDS-repacked 8B system-scope (write-through) stores into hist ring;
// plain cached loads kept fresh by ring depth 32 + acquire fence every 8 steps.
// out3 ALIASES WT (dead after prologue counter-barrier).
// ---------------------------------------------------------------------------
__global__ __launch_bounds__(256, 1) void lstm_main(
    const u16* __restrict__ WT, const float* __restrict__ emb,
    const int* __restrict__ ids, const float* __restrict__ bias,
    u16* __restrict__ hist, const u16* __restrict__ zbuf,
    u16* __restrict__ out3, unsigned* __restrict__ bar)
{
  __shared__ float lpart[4][48][68];   // [src wave][3 m-tiles *16][64 cols+pad]
  __shared__ __align__(16) u16 hs[64][16];  // h repack tile (rows 0..63 x units u0..u0+15)
  const int tid = threadIdx.x;
  const int w = tid >> 6;            // wave id (K-split, and cell-update row group)
  const int lane = tid & 63;
  const int lm = lane & 15, qk = lane >> 4;
  const int bid = blockIdx.x;
  const int stage = bid >> 5;
  const int slice = bid & 31;
  const int u0 = slice * 16;
  const int d = stage / 3, l = stage - 3 * d;

  unsigned* flags = bar + 16;                       // 6*32 words
  unsigned* fO = flags + stage * 32;
  unsigned* fP = flags + (l > 0 ? (stage - 1) : stage) * 32;
  unsigned* fC = flags + (l < 2 ? (stage + 1) : stage) * 32;
  unsigned* myf = fO + slice;

  // B fragments: col = nt*512 + u0 + lm (gate nt), k = w*256 + ks*32 + qk*8
  s8v bfr[8][4];
#pragma unroll
  for (int ks = 0; ks < 8; ++ks)
#pragma unroll
    for (int nt = 0; nt < 4; ++nt)
      bfr[ks][nt] = *(const s8v*)(WT + ((size_t)stage * 2048 + nt * 512 + u0 + lm) * 1024
                                  + w * 256 + ks * 32 + qk * 8);
  float bias4[4];
#pragma unroll
  for (int nt = 0; nt < 4; ++nt)
    bias4[nt] = bias[((size_t)d * 3 + l) * 2048 + nt * 512 + u0 + lm];

  float c[4] = {0.f, 0.f, 0.f, 0.f};      // cell state, rows 16w+qk*4+r, unit u0+lm
  const int brow = 16 * w + qk * 4;
  const f4v fzero = {0.f, 0.f, 0.f, 0.f};

  // One-time barrier: all B-frag reads complete before out3 tramples WT.
  __syncthreads();
  if (tid == 0) {
    __hip_atomic_fetch_add(bar, 1u, __ATOMIC_RELAXED, __HIP_MEMORY_SCOPE_AGENT);
    while (__hip_atomic_load(bar, __ATOMIC_RELAXED, __HIP_MEMORY_SCOPE_AGENT) < (unsigned)NBLK)
      __builtin_amdgcn_s_sleep(2);
  }
  __syncthreads();

  for (int s = 0; s < 258; ++s) {
    // ---- dependency wait (wave 0 polls; one LLC round trip per iteration) ----
    if (w == 0) {
      const unsigned sU = (unsigned)s;
      for (;;) {
        bool ok = true;
        if (lane < 32) {
          unsigned vO = __hip_atomic_load(fO + lane, __ATOMIC_RELAXED, __HIP_MEMORY_SCOPE_AGENT);
          ok = (vO >= sU);
          if (l > 0) {
            unsigned vP = __hip_atomic_load(fP + lane, __ATOMIC_RELAXED, __HIP_MEMORY_SCOPE_AGENT);
            ok = ok && (vP >= sU);
          }
          if (l < 2) {
            int vC = (int)__hip_atomic_load(fC + lane, __ATOMIC_RELAXED, __HIP_MEMORY_SCOPE_AGENT);
            ok = ok && (vC >= s - 24);
          }
        }
        if (__all(ok)) break;
      }
      if (tid == 0 && (s & 7) == 7)
        __builtin_amdgcn_fence(__ATOMIC_ACQUIRE, "agent");  // periodic inv: staleness bound 8 < 32
    }
    __syncthreads();

    int t = s - l;
    if (t >= 0 && t < 256) {
      int tx = d ? (255 - t) : t;        // time index into input sequence
      const u16* lo;
      const u16* hi;
      if (l == 0) {
        lo = (t == 0) ? zbuf
             : hist + ((size_t)((t - 1) & (HDEPTH - 1)) * 6 + stage) * 64 * 512;  // h1[t-1]
        hi = lo;                                                  // unused (emb path)
      } else {
        lo = hist + ((size_t)(t & (HDEPTH - 1)) * 6 + (stage - 1)) * 64 * 512;    // h_{l-1}[t]
        hi = (t == 0) ? zbuf
             : hist + ((size_t)((t - 1) & (HDEPTH - 1)) * 6 + stage) * 64 * 512;  // h_l[t-1]
      }

      f4v acc[4][4];
#pragma unroll
      for (int mt = 0; mt < 4; ++mt)
#pragma unroll
        for (int nt = 0; nt < 4; ++nt) acc[mt][nt] = fzero;

      if (l == 0 && w >= 2) {
        // ---- input-projection side: A = emb[ids[row][tx]] (float row, 16B aligned) ----
        if (w == 2) {                    // j in [0,256): all fragments fully valid
#pragma unroll
          for (int mt = 0; mt < 4; ++mt) {
            const int id = ids[(mt * 16 + lm) * 256 + tx];
            const float* er = emb + (size_t)id * 300;
#pragma unroll
            for (int ks = 0; ks < 8; ++ks) {
              f4v f0 = *(const f4v*)(er + ks * 32 + qk * 8);
              f4v f1 = *(const f4v*)(er + ks * 32 + qk * 8 + 4);
              s8v a = cvt8(f0, f1);
#pragma unroll
              for (int nt = 0; nt < 4; ++nt)
                acc[mt][nt] = __builtin_amdgcn_mfma_f32_16x16x32_bf16(a, bfr[ks][nt], acc[mt][nt], 0, 0, 0);
            }
          }
        } else {                         // w==3: j in [256,512); only ks 0,1 nonzero
#pragma unroll
          for (int mt = 0; mt < 4; ++mt) {
            const int id = ids[(mt * 16 + lm) * 256 + tx];
            const float* er = emb + (size_t)id * 300;
            {                            // ks=0: j 256..287 all valid
              f4v f0 = *(const f4v*)(er + 256 + qk * 8);
              f4v f1 = *(const f4v*)(er + 256 + qk * 8 + 4);
              s8v a0 = cvt8(f0, f1);
#pragma unroll
              for (int nt = 0; nt < 4; ++nt)
                acc[mt][nt] = __builtin_amdgcn_mfma_f32_16x16x32_bf16(a0, bfr[0][nt], acc[mt][nt], 0, 0, 0);
            }
            {                            // ks=1: j 288..319; valid only j<300
              s8v a1;
              if (qk == 0) {             // j 288..295
                f4v f0 = *(const f4v*)(er + 288);
                f4v f1 = *(const f4v*)(er + 292);
                a1 = cvt8(f0, f1);
              } else if (qk == 1) {      // j 296..303: 296..299 valid, rest zero
                f4v f0 = *(const f4v*)(er + 296);
                a1 = cvt8(f0, fzero);
              } else {                   // j >= 304: WT rows are zero anyway
                a1 = (s8v){0,0,0,0,0,0,0,0};
              }
#pragma unroll
              for (int nt = 0; nt < 4; ++nt)
                acc[mt][nt] = __builtin_amdgcn_mfma_f32_16x16x32_bf16(a1, bfr[1][nt], acc[mt][nt], 0, 0, 0);
            }
            // ks 2..7 contribute zero (WT rows >= 832 are 0): skipped
          }
        }
      } else {
        // ---- standard h-side path (plain cached loads; addresses are fresh) ----
        const u16* aptr = (w < 2) ? lo : hi;
        const int koff = (w & 1) * 256;
#pragma unroll
        for (int ks = 0; ks < 8; ++ks) {
#pragma unroll
          for (int mt = 0; mt < 4; ++mt) {
            s8v a = *(const s8v*)(aptr + (size_t)(mt * 16 + lm) * 512 + koff + ks * 32 + qk * 8);
#pragma unroll
            for (int nt = 0; nt < 4; ++nt)
              acc[mt][nt] = __builtin_amdgcn_mfma_f32_16x16x32_bf16(a, bfr[ks][nt], acc[mt][nt], 0, 0, 0);
          }
        }
      }

      // cross-wave K reduction: wave w keeps m-tile w, ships the other three
#pragma unroll
      for (int mt = 0; mt < 4; ++mt) {
        if (mt == w) continue;
        int slot = mt - (mt > w ? 1 : 0);
#pragma unroll
        for (int nt = 0; nt < 4; ++nt)
#pragma unroll
          for (int r = 0; r < 4; ++r)
            lpart[w][slot * 16 + qk * 4 + r][nt * 16 + lm] = acc[mt][nt][r];
      }
      __syncthreads();

      float z[4][4];
#pragma unroll
      for (int nt = 0; nt < 4; ++nt)
#pragma unroll
        for (int r = 0; r < 4; ++r) {
          float v = acc[w][nt][r];
#pragma unroll
          for (int ps = 0; ps < 4; ++ps) {
            if (ps == w) continue;
            int slot = w - (w > ps ? 1 : 0);
            v += lpart[ps][slot * 16 + qk * 4 + r][nt * 16 + lm];
          }
          z[nt][r] = v + bias4[nt];
        }

      // cell update: i,f,g,o = z[0..3]; stage h into LDS for wide stores
#pragma unroll
      for (int r = 0; r < 4; ++r) {
        float zi = z[0][r], zf = z[1][r], zg = z[2][r], zo = z[3][r];
        float si = 1.f / (1.f + __expf(-zi));
        float sf = 1.f / (1.f + __expf(-zf));
        float so = 1.f / (1.f + __expf(-zo));
        float sg = zg / (1.f + fabsf(zg));
        float cn = sf * c[r] + si * sg;
        c[r] = cn;
        float h = so * (cn / (1.f + fabsf(cn)));
        hs[brow + r][lm] = f2b(h);
      }
      __syncthreads();

      // cooperative write-through: 256 threads x 8B (was 1024 x 2B)
      u16* hq = hist + ((size_t)(t & (HDEPTH - 1)) * 6 + stage) * 64 * 512;
      int row = tid >> 2, part = tid & 3;
      u64 v8 = *(const u64*)&hs[row][part * 4];
      size_t off = (size_t)row * 512 + u0 + part * 4;
      __hip_atomic_store((u64*)(hq + off), v8, __ATOMIC_RELAXED, __HIP_MEMORY_SCOPE_SYSTEM);
      if (l == 2)
        *(u64*)(out3 + ((size_t)d * 256 + t) * 64 * 512 + off) = v8;  // plain cached store
    }
    __syncthreads();   // drain all stores (vmcnt(0) per wave) before publishing
    if (tid == 0)
      __hip_atomic_store(myf, (unsigned)(s + 1), __ATOMIC_RELAXED, __HIP_MEMORY_SCOPE_SYSTEM);
  }
}

// ---------------------------------------------------------------------------
// Attention scores: per t-block, enc = 0.5*(out3[0][t]+out3[1][t]) on the fly,
// a = prelu(enc@Wa0+ba0), scores[b][t] = a@Wa1 + ba1.
// ---------------------------------------------------------------------------
__global__ __launch_bounds__(256) void attn_scores(
    const u16* __restrict__ out3, const u16* __restrict__ WaT,
    const float* __restrict__ ba0, const float* __restrict__ alpha_a,
    const float* __restrict__ Wa1, const float* __restrict__ ba1,
    float* __restrict__ scores)
{
  int t = blockIdx.x, tid = threadIdx.x;
  int w = tid >> 6, lane = tid & 63, lm = lane & 15, qk = lane >> 4;
  const u16* e0 = out3 + (size_t)t * 64 * 512;
  const u16* e1 = out3 + ((size_t)256 + t) * 64 * 512;
  const f4v fzero = {0.f, 0.f, 0.f, 0.f};
  f4v acc[16];
#pragma unroll
  for (int nt = 0; nt < 16; ++nt) acc[nt] = fzero;

  for (int ks = 0; ks < 16; ++ks) {
    size_t aoff = (size_t)(16 * w + lm) * 512 + ks * 32 + qk * 8;
    s8v a0 = *(const s8v*)(e0 + aoff);
    s8v a1 = *(const s8v*)(e1 + aoff);
    s8v af;
#pragma unroll
    for (int j = 0; j < 8; ++j)
      af[j] = (short)f2b(0.5f * (b2f((u16)a0[j]) + b2f((u16)a1[j])));
#pragma unroll
    for (int nt = 0; nt < 16; ++nt) {
      s8v bf = *(const s8v*)(WaT + (size_t)(nt * 16 + lm) * 512 + ks * 32 + qk * 8);
      acc[nt] = __builtin_amdgcn_mfma_f32_16x16x32_bf16(af, bf, acc[nt], 0, 0, 0);
    }
  }

  float sums[4] = {0.f, 0.f, 0.f, 0.f};
#pragma unroll
  for (int nt = 0; nt < 16; ++nt) {
    int col = nt * 16 + lm;
    float bb = ba0[col];
    float al = alpha_a[col];
    float wv = Wa1[col];
#pragma unroll
    for (int r = 0; r < 4; ++r) {
      float v = acc[nt][r] + bb;
      v = (v >= 0.f) ? v : al * v;
      sums[r] += v * wv;
    }
  }
  float bb1 = ba1[0];
#pragma unroll
  for (int r = 0; r < 4; ++r) {
    float v = sums[r];
    v += __shfl_xor(v, 1, 16);
    v += __shfl_xor(v, 2, 16);
    v += __shfl_xor(v, 4, 16);
    v += __shfl_xor(v, 8, 16);
    if (lm == 0) {
      int b = 16 * w + qk * 4 + r;
      scores[(size_t)b * 256 + t] = v + bb1;
    }
  }
}

// ---------------------------------------------------------------------------
// Softmax over T + pooled[b][u] = sum_t w[t]*enc[b][t][u]
// ---------------------------------------------------------------------------
__global__ __launch_bounds__(256) void attn_pool(
    const u16* __restrict__ out3, const float* __restrict__ scores,
    u16* __restrict__ pooled)
{
  __shared__ float red[256];
  __shared__ float wts[256];
  int b = blockIdx.x, tid = threadIdx.x;
  float s = scores[(size_t)b * 256 + tid];
  red[tid] = s; __syncthreads();
  for (int o = 128; o > 0; o >>= 1) { if (tid < o) red[tid] = fmaxf(red[tid], red[tid + o]); __syncthreads(); }
  float m = red[0]; __syncthreads();
  float e = __expf(s - m);
  red[tid] = e; __syncthreads();
  for (int o = 128; o > 0; o >>= 1) { if (tid < o) red[tid] += red[tid + o]; __syncthreads(); }
  float inv = 1.f / red[0];
  wts[tid] = e * inv; __syncthreads();

  int u2 = tid * 2;
  float a0 = 0.f, a1 = 0.f;
#pragma unroll 4
  for (int t = 0; t < 256; ++t) {
    float wt = wts[t];
    const ushort2 v0 = *(const ushort2*)(out3 + ((size_t)t * 64 + b) * 512 + u2);
    const ushort2 v1 = *(const ushort2*)(out3 + (((size_t)256 + t) * 64 + b) * 512 + u2);
    a0 += wt * 0.5f * (b2f(v0.x) + b2f(v1.x));
    a1 += wt * 0.5f * (b2f(v0.y) + b2f(v1.y));
  }
  pooled[(size_t)b * 512 + u2] = f2b(a0);
  pooled[(size_t)b * 512 + u2 + 1] = f2b(a1);
}

// ---------------------------------------------------------------------------
// Head: h = prelu(BN(pooled@Wd0+bd0)); out = softmax(h@Wd1+bd1)  (float out)
// ---------------------------------------------------------------------------
__global__ __launch_bounds__(256) void head(
    const u16* __restrict__ pooled, const u16* __restrict__ WdT,
    const float* __restrict__ bd0, const float* __restrict__ gamma,
    const float* __restrict__ beta, const float* __restrict__ bn_mean,
    const float* __restrict__ bn_var, const float* __restrict__ alpha_h,
    const float* __restrict__ Wd1, const float* __restrict__ bd1,
    float* __restrict__ outp)
{
  __shared__ float hl[64][260];
  __shared__ float lg[64][8];
  int tid = threadIdx.x;
  int w = tid >> 6, lane = tid & 63, lm = lane & 15, qk = lane >> 4;
  const f4v fzero = {0.f, 0.f, 0.f, 0.f};
  f4v acc[16];
#pragma unroll
  for (int nt = 0; nt < 16; ++nt) acc[nt] = fzero;
  for (int ks = 0; ks < 16; ++ks) {
    s8v a = *(const s8v*)(pooled + (size_t)(16 * w + lm) * 512 + ks * 32 + qk * 8);
#pragma unroll
    for (int nt = 0; nt < 16; ++nt) {
      s8v bf = *(const s8v*)(WdT + (size_t)(nt * 16 + lm) * 512 + ks * 32 + qk * 8);
      acc[nt] = __builtin_amdgcn_mfma_f32_16x16x32_bf16(a, bf, acc[nt], 0, 0, 0);
    }
  }
#pragma unroll
  for (int nt = 0; nt < 16; ++nt) {
    int col = nt * 16 + lm;
    float mn = bn_mean[col];
    float sc = gamma[col] * rsqrtf(bn_var[col] + 1e-3f);
    float be = beta[col];
    float al = alpha_h[col];
    float b0 = bd0[col];
#pragma unroll
    for (int r = 0; r < 4; ++r) {
      float v = acc[nt][r] + b0;
      v = (v - mn) * sc + be;
      v = (v >= 0.f) ? v : al * v;
      hl[16 * w + qk * 4 + r][col] = v;
    }
  }
  __syncthreads();
  for (int idx = tid; idx < 448; idx += 256) {
    int b = idx / 7, cc = idx - b * 7;
    float sv = bd1[cc];
    for (int k = 0; k < 256; ++k) sv += hl[b][k] * Wd1[k * 7 + cc];
    lg[b][cc] = sv;
  }
  __syncthreads();
  if (tid < 64) {
    float mx = -1e30f;
#pragma unroll
    for (int cc = 0; cc < 7; ++cc) mx = fmaxf(mx, lg[tid][cc]);
    float sum = 0.f; float ex[7];
#pragma unroll
    for (int cc = 0; cc < 7; ++cc) { ex[cc] = __expf(lg[tid][cc] - mx); sum += ex[cc]; }
    float inv = 1.f / sum;
#pragma unroll
    for (int cc = 0; cc < 7; ++cc) outp[tid * 7 + cc] = ex[cc] * inv;
  }
}

// ---------------------------------------------------------------------------
extern "C" void kernel_launch(void* const* d_in, const int* in_sizes, int n_in,
                              void* d_out, int out_size, void* d_ws, size_t ws_size,
                              hipStream_t stream)
{
  (void)in_sizes; (void)n_in; (void)out_size; (void)ws_size;
  const int*   ids     = (const int*)d_in[0];
  const float* emb     = (const float*)d_in[1];
  const float* k0      = (const float*)d_in[2];
  const float* k12     = (const float*)d_in[3];
  const float* rec     = (const float*)d_in[4];
  const float* bias    = (const float*)d_in[5];
  const float* Wa0     = (const float*)d_in[6];
  const float* ba0     = (const float*)d_in[7];
  const float* alpha_a = (const float*)d_in[8];
  const float* Wa1     = (const float*)d_in[9];
  const float* ba1     = (const float*)d_in[10];
  const float* Wd0     = (const float*)d_in[11];
  const float* bd0     = (const float*)d_in[12];
  const float* gamma   = (const float*)d_in[13];
  const float* beta    = (const float*)d_in[14];
  const float* bn_mean = (const float*)d_in[15];
  const float* bn_var  = (const float*)d_in[16];
  const float* alpha_h = (const float*)d_in[17];
  const float* Wd1     = (const float*)d_in[18];
  const float* bd1     = (const float*)d_in[19];

  char* ws = (char*)d_ws;
  // out3 (33,554,432 B) ALIASES WT (25,165,824 B): WT is dead once lstm_main's
  // prologue barrier passes (B-frags register-resident); out3 writes start after.
  u16* WT      = (u16*)(ws);                    // [0, 25.17 MB)
  u16* out3    = (u16*)(ws);                    // [0, 33.55 MB)
  u16* hist    = (u16*)(ws + 33554432);         // 32*6*64*512*2 = 12,582,912
  u16* WaT     = (u16*)(ws + 46137344);         // 262,144
  u16* WdT     = (u16*)(ws + 46399488);         // 262,144
  float* scores= (float*)(ws + 46661632);       // 65,536
  u16* pooled  = (u16*)(ws + 46727168);         // 65,536
  u16* zbuf    = (u16*)(ws + 46792704);         // 65,536 (zero tile)
  unsigned* bar= (unsigned*)(ws + 46858240);    // [0]=prologue counter, +16: 192 flags (832 B)
                                                // total 46,859,264 B

  hipMemsetAsync(zbuf, 0, 65536, stream);
  hipMemsetAsync(bar, 0, 1024, stream);

  prep_weights<<<dim3(3136), dim3(256), 0, stream>>>(k0, k12, rec, Wa0, Wd0, WT, WaT, WdT);

  void* args[] = { (void*)&WT, (void*)&emb, (void*)&ids, (void*)&bias,
                   (void*)&hist, (void*)&zbuf, (void*)&out3, (void*)&bar };
  hipLaunchCooperativeKernel((void*)lstm_main, dim3(NBLK), dim3(256), args, 0, stream);

  attn_scores<<<dim3(256), dim3(256), 0, stream>>>(out3, WaT, ba0, alpha_a, Wa1, ba1, scores);
  attn_pool<<<dim3(64), dim3(256), 0, stream>>>(out3, scores, pooled);
  head<<<dim3(1), dim3(256), 0, stream>>>(pooled, WdT, bd0, gamma, beta, bn_mean, bn_var,
                                          alpha_h, Wd1, bd1, (float*)d_out);
}

// Round 7
// 5457.302 us; speedup vs baseline: 1.9091x; 1.0072x over previous
//
#include <hip/hip_runtime.h>
#include <hip/hip_bf16.h>

typedef short s8v __attribute__((ext_vector_type(8)));   // 8 bf16 (4 VGPRs) MFMA frag
typedef float f4v __attribute__((ext_vector_type(4)));   // MFMA accum frag / float4 load

#define NBLK 192   // 6 stages * 32 blocks
#define HDEPTH 32  // h-history ring depth (address reuse distance)

typedef unsigned short u16;
typedef unsigned long long u64;

__device__ __forceinline__ float b2f(u16 u) {
  union { unsigned int i; float f; } v; v.i = ((unsigned int)u) << 16; return v.f;
}
__device__ __forceinline__ u16 f2b(float f) {
  union { float f; unsigned int i; } v; v.f = f;
  unsigned int x = v.i;
  return (u16)((x + 0x7fffu + ((x >> 16) & 1u)) >> 16);  // RNE
}
__device__ __forceinline__ s8v cvt8(f4v a, f4v b) {
  s8v r;
  r[0] = (short)f2b(a[0]); r[1] = (short)f2b(a[1]);
  r[2] = (short)f2b(a[2]); r[3] = (short)f2b(a[3]);
  r[4] = (short)f2b(b[0]); r[5] = (short)f2b(b[1]);
  r[6] = (short)f2b(b[2]); r[7] = (short)f2b(b[3]);
  return r;
}

// ---------------------------------------------------------------------------
// P1: build transposed bf16 weights from float32 sources.
// WT[stage][col 0..2047][k 0..1023] (bf16), stage = d*3+l:
//   l==0 : k<512 -> rec[d][0][k][col];  k-512 in [0,300) -> k0[d][k-512][col]; else 0
//   l>=1 : k<512 -> k12[d][l-1][k][col]; else rec[d][l][k-512][col]
// WaT[n][k] = Wa0[k][n];  WdT likewise for Wd0.
// ---------------------------------------------------------------------------
__global__ __launch_bounds__(256) void prep_weights(
    const float* __restrict__ k0, const float* __restrict__ k12,
    const float* __restrict__ rec, const float* __restrict__ Wa0,
    const float* __restrict__ Wd0,
    u16* __restrict__ WT, u16* __restrict__ WaT, u16* __restrict__ WdT)
{
  __shared__ u16 tl[64][65];
  int bid = blockIdx.x, tid = threadIdx.x;
  if (bid < 3072) {
    int stage = bid >> 9;
    int t2 = bid & 511;
    int ct = t2 >> 4, kt = t2 & 15;
    int d = stage / 3, l = stage - 3 * d;
    int colbase = ct * 64, kbase = kt * 64;
    int cl = tid & 63;
#pragma unroll
    for (int i = 0; i < 16; ++i) {
      int kl = i * 4 + (tid >> 6);
      int k = kbase + kl, col = colbase + cl;
      float v;
      if (l == 0) {
        if (k < 512) v = rec[((size_t)(d * 3 + 0) * 512 + k) * 2048 + col];
        else { int j = k - 512; v = (j < 300) ? k0[((size_t)d * 300 + j) * 2048 + col] : 0.f; }
      } else {
        if (k < 512) v = k12[((size_t)(d * 2 + (l - 1)) * 512 + k) * 2048 + col];
        else         v = rec[((size_t)(d * 3 + l) * 512 + (k - 512)) * 2048 + col];
      }
      tl[kl][cl] = f2b(v);
    }
    __syncthreads();
#pragma unroll
    for (int i = 0; i < 16; ++i) {
      int cl2 = i * 4 + (tid >> 6);
      int kl2 = tid & 63;
      WT[((size_t)stage * 2048 + colbase + cl2) * 1024 + kbase + kl2] = tl[kl2][cl2];
    }
  } else {
    int m = bid - 3072;
    int mat = m >> 5, tt = m & 31;
    int nt = tt & 3, kt = tt >> 2;
    const float* src = mat ? Wd0 : Wa0;
    u16* dst = mat ? WdT : WaT;
    int nbase = nt * 64, kbase = kt * 64;
    int cl = tid & 63;
#pragma unroll
    for (int i = 0; i < 16; ++i) {
      int kl = i * 4 + (tid >> 6);
      tl[kl][cl] = f2b(src[(size_t)(kbase + kl) * 256 + nbase + cl]);
    }
    __syncthreads();
#pragma unroll
    for (int i = 0; i < 16; ++i) {
      int nl = i * 4 + (tid >> 6);
      int kl = tid & 63;
      dst[(size_t)(nbase + nl) * 512 + kbase + kl] = tl[kl][nl];
    }
  }
}

// ---------------------------------------------------------------------------
// Main persistent LSTM kernel.  192 blocks: stage = bid>>5 (d*3+l), slice = bid&31.
// Dependency-flag pipeline sync (NO global barrier):
//   flags[stage*32+slice] = completed_step+1 (4B AGENT-scope store -> LLC).
//   At step s a block waits: own stage >= s, producer stage (l-1) >= s,
//   consumer stage (l+1) >= s-24 (WAR backpressure for the 32-deep h ring).
// h: LDS-repacked 8B AGENT-scope (LLC write-through) stores into hist ring;
// plain cached loads kept fresh by ring depth 32 + acquire fence every 8 steps.
// out3 ALIASES WT (dead after prologue counter-barrier).
// ---------------------------------------------------------------------------
__global__ __launch_bounds__(256, 1) void lstm_main(
    const u16* __restrict__ WT, const float* __restrict__ emb,
    const int* __restrict__ ids, const float* __restrict__ bias,
    u16* __restrict__ hist, const u16* __restrict__ zbuf,
    u16* __restrict__ out3, unsigned* __restrict__ bar)
{
  __shared__ float lpart[4][48][68];   // [src wave][3 m-tiles *16][64 cols+pad]
  __shared__ __align__(16) u16 hs[64][20];  // h repack tile, padded row (40B) vs bank conflicts
  const int tid = threadIdx.x;
  const int w = tid >> 6;            // wave id (K-split, and cell-update row group)
  const int lane = tid & 63;
  const int lm = lane & 15, qk = lane >> 4;
  const int bid = blockIdx.x;
  const int stage = bid >> 5;
  const int slice = bid & 31;
  const int u0 = slice * 16;
  const int d = stage / 3, l = stage - 3 * d;

  unsigned* flags = bar + 16;                       // 6*32 words
  unsigned* fO = flags + stage * 32;
  unsigned* fP = flags + (l > 0 ? (stage - 1) : stage) * 32;
  unsigned* fC = flags + (l < 2 ? (stage + 1) : stage) * 32;
  unsigned* myf = fO + slice;

  // B fragments: col = nt*512 + u0 + lm (gate nt), k = w*256 + ks*32 + qk*8
  s8v bfr[8][4];
#pragma unroll
  for (int ks = 0; ks < 8; ++ks)
#pragma unroll
    for (int nt = 0; nt < 4; ++nt)
      bfr[ks][nt] = *(const s8v*)(WT + ((size_t)stage * 2048 + nt * 512 + u0 + lm) * 1024
                                  + w * 256 + ks * 32 + qk * 8);
  float bias4[4];
#pragma unroll
  for (int nt = 0; nt < 4; ++nt)
    bias4[nt] = bias[((size_t)d * 3 + l) * 2048 + nt * 512 + u0 + lm];

  float c[4] = {0.f, 0.f, 0.f, 0.f};      // cell state, rows 16w+qk*4+r, unit u0+lm
  const int brow = 16 * w + qk * 4;
  const f4v fzero = {0.f, 0.f, 0.f, 0.f};

  // One-time barrier: all B-frag reads complete before out3 tramples WT.
  __syncthreads();
  if (tid == 0) {
    __hip_atomic_fetch_add(bar, 1u, __ATOMIC_RELAXED, __HIP_MEMORY_SCOPE_AGENT);
    while (__hip_atomic_load(bar, __ATOMIC_RELAXED, __HIP_MEMORY_SCOPE_AGENT) < (unsigned)NBLK)
      __builtin_amdgcn_s_sleep(2);
  }
  __syncthreads();

  for (int s = 0; s < 258; ++s) {
    // ---- dependency wait (wave 0 polls LLC; s_sleep throttles fabric traffic) ----
    if (w == 0) {
      const unsigned sU = (unsigned)s;
      for (;;) {
        bool ok = true;
        if (lane < 32) {
          unsigned vO = __hip_atomic_load(fO + lane, __ATOMIC_RELAXED, __HIP_MEMORY_SCOPE_AGENT);
          ok = (vO >= sU);
          if (l > 0) {
            unsigned vP = __hip_atomic_load(fP + lane, __ATOMIC_RELAXED, __HIP_MEMORY_SCOPE_AGENT);
            ok = ok && (vP >= sU);
          }
          if (l < 2) {
            int vC = (int)__hip_atomic_load(fC + lane, __ATOMIC_RELAXED, __HIP_MEMORY_SCOPE_AGENT);
            ok = ok && (vC >= s - 24);
          }
        }
        if (__all(ok)) break;
        __builtin_amdgcn_s_sleep(4);
      }
      if (tid == 0 && (s & 7) == 7)
        __builtin_amdgcn_fence(__ATOMIC_ACQUIRE, "agent");  // periodic inv: staleness bound 8 < 32
    }
    __syncthreads();

    int t = s - l;
    if (t >= 0 && t < 256) {
      int tx = d ? (255 - t) : t;        // time index into input sequence
      const u16* lo;
      const u16* hi;
      if (l == 0) {
        lo = (t == 0) ? zbuf
             : hist + ((size_t)((t - 1) & (HDEPTH - 1)) * 6 + stage) * 64 * 512;  // h1[t-1]
        hi = lo;                                                  // unused (emb path)
      } else {
        lo = hist + ((size_t)(t & (HDEPTH - 1)) * 6 + (stage - 1)) * 64 * 512;    // h_{l-1}[t]
        hi = (t == 0) ? zbuf
             : hist + ((size_t)((t - 1) & (HDEPTH - 1)) * 6 + stage) * 64 * 512;  // h_l[t-1]
      }

      f4v acc[4][4];
#pragma unroll
      for (int mt = 0; mt < 4; ++mt)
#pragma unroll
        for (int nt = 0; nt < 4; ++nt) acc[mt][nt] = fzero;

      if (l == 0 && w >= 2) {
        // ---- input-projection side: A = emb[ids[row][tx]] (float row, 16B aligned) ----
        if (w == 2) {                    // j in [0,256): all fragments fully valid
#pragma unroll
          for (int mt = 0; mt < 4; ++mt) {
            const int id = ids[(mt * 16 + lm) * 256 + tx];
            const float* er = emb + (size_t)id * 300;
#pragma unroll
            for (int ks = 0; ks < 8; ++ks) {
              f4v f0 = *(const f4v*)(er + ks * 32 + qk * 8);
              f4v f1 = *(const f4v*)(er + ks * 32 + qk * 8 + 4);
              s8v a = cvt8(f0, f1);
#pragma unroll
              for (int nt = 0; nt < 4; ++nt)
                acc[mt][nt] = __builtin_amdgcn_mfma_f32_16x16x32_bf16(a, bfr[ks][nt], acc[mt][nt], 0, 0, 0);
            }
          }
        } else {                         // w==3: j in [256,512); only ks 0,1 nonzero
#pragma unroll
          for (int mt = 0; mt < 4; ++mt) {
            const int id = ids[(mt * 16 + lm) * 256 + tx];
            const float* er = emb + (size_t)id * 300;
            {                            // ks=0: j 256..287 all valid
              f4v f0 = *(const f4v*)(er + 256 + qk * 8);
              f4v f1 = *(const f4v*)(er + 256 + qk * 8 + 4);
              s8v a0 = cvt8(f0, f1);
#pragma unroll
              for (int nt = 0; nt < 4; ++nt)
                acc[mt][nt] = __builtin_amdgcn_mfma_f32_16x16x32_bf16(a0, bfr[0][nt], acc[mt][nt], 0, 0, 0);
            }
            {                            // ks=1: j 288..319; valid only j<300
              s8v a1;
              if (qk == 0) {             // j 288..295
                f4v f0 = *(const f4v*)(er + 288);
                f4v f1 = *(const f4v*)(er + 292);
                a1 = cvt8(f0, f1);
              } else if (qk == 1) {      // j 296..303: 296..299 valid, rest zero
                f4v f0 = *(const f4v*)(er + 296);
                a1 = cvt8(f0, fzero);
              } else {                   // j >= 304: WT rows are zero anyway
                a1 = (s8v){0,0,0,0,0,0,0,0};
              }
#pragma unroll
              for (int nt = 0; nt < 4; ++nt)
                acc[mt][nt] = __builtin_amdgcn_mfma_f32_16x16x32_bf16(a1, bfr[1][nt], acc[mt][nt], 0, 0, 0);
            }
            // ks 2..7 contribute zero (WT rows >= 832 are 0): skipped
          }
        }
      } else {
        // ---- standard h-side path (plain cached loads; addresses are fresh) ----
        const u16* aptr = (w < 2) ? lo : hi;
        const int koff = (w & 1) * 256;
#pragma unroll
        for (int ks = 0; ks < 8; ++ks) {
#pragma unroll
          for (int mt = 0; mt < 4; ++mt) {
            s8v a = *(const s8v*)(aptr + (size_t)(mt * 16 + lm) * 512 + koff + ks * 32 + qk * 8);
#pragma unroll
            for (int nt = 0; nt < 4; ++nt)
              acc[mt][nt] = __builtin_amdgcn_mfma_f32_16x16x32_bf16(a, bfr[ks][nt], acc[mt][nt], 0, 0, 0);
          }
        }
      }

      // cross-wave K reduction: wave w keeps m-tile w, ships the other three
#pragma unroll
      for (int mt = 0; mt < 4; ++mt) {
        if (mt == w) continue;
        int slot = mt - (mt > w ? 1 : 0);
#pragma unroll
        for (int nt = 0; nt < 4; ++nt)
#pragma unroll
          for (int r = 0; r < 4; ++r)
            lpart[w][slot * 16 + qk * 4 + r][nt * 16 + lm] = acc[mt][nt][r];
      }
      __syncthreads();

      float z[4][4];
#pragma unroll
      for (int nt = 0; nt < 4; ++nt)
#pragma unroll
        for (int r = 0; r < 4; ++r) {
          float v = acc[w][nt][r];
#pragma unroll
          for (int ps = 0; ps < 4; ++ps) {
            if (ps == w) continue;
            int slot = w - (w > ps ? 1 : 0);
            v += lpart[ps][slot * 16 + qk * 4 + r][nt * 16 + lm];
          }
          z[nt][r] = v + bias4[nt];
        }

      // cell update: i,f,g,o = z[0..3]; stage h into LDS for wide stores
#pragma unroll
      for (int r = 0; r < 4; ++r) {
        float zi = z[0][r], zf = z[1][r], zg = z[2][r], zo = z[3][r];
        float si = 1.f / (1.f + __expf(-zi));
        float sf = 1.f / (1.f + __expf(-zf));
        float so = 1.f / (1.f + __expf(-zo));
        float sg = zg / (1.f + fabsf(zg));
        float cn = sf * c[r] + si * sg;
        c[r] = cn;
        float h = so * (cn / (1.f + fabsf(cn)));
        hs[brow + r][lm] = f2b(h);
      }
      __syncthreads();

      // cooperative write-through to LLC: 256 threads x 8B agent-scope stores
      u16* hq = hist + ((size_t)(t & (HDEPTH - 1)) * 6 + stage) * 64 * 512;
      int row = tid >> 2, part = tid & 3;
      u64 v8 = *(const u64*)&hs[row][part * 4];
      size_t off = (size_t)row * 512 + u0 + part * 4;
      __hip_atomic_store((u64*)(hq + off), v8, __ATOMIC_RELAXED, __HIP_MEMORY_SCOPE_AGENT);
      if (l == 2)
        *(u64*)(out3 + ((size_t)d * 256 + t) * 64 * 512 + off) = v8;  // plain cached store
    }
    __syncthreads();   // drain all stores (vmcnt(0) per wave) before publishing
    if (tid == 0)
      __hip_atomic_store(myf, (unsigned)(s + 1), __ATOMIC_RELAXED, __HIP_MEMORY_SCOPE_AGENT);
  }
}

// ---------------------------------------------------------------------------
// Attention scores: per t-block, enc = 0.5*(out3[0][t]+out3[1][t]) on the fly,
// a = prelu(enc@Wa0+ba0), scores[b][t] = a@Wa1 + ba1.
// ---------------------------------------------------------------------------
__global__ __launch_bounds__(256) void attn_scores(
    const u16* __restrict__ out3, const u16* __restrict__ WaT,
    const float* __restrict__ ba0, const float* __restrict__ alpha_a,
    const float* __restrict__ Wa1, const float* __restrict__ ba1,
    float* __restrict__ scores)
{
  int t = blockIdx.x, tid = threadIdx.x;
  int w = tid >> 6, lane = tid & 63, lm = lane & 15, qk = lane >> 4;
  const u16* e0 = out3 + (size_t)t * 64 * 512;
  const u16* e1 = out3 + ((size_t)256 + t) * 64 * 512;
  const f4v fzero = {0.f, 0.f, 0.f, 0.f};
  f4v acc[16];
#pragma unroll
  for (int nt = 0; nt < 16; ++nt) acc[nt] = fzero;

  for (int ks = 0; ks < 16; ++ks) {
    size_t aoff = (size_t)(16 * w + lm) * 512 + ks * 32 + qk * 8;
    s8v a0 = *(const s8v*)(e0 + aoff);
    s8v a1 = *(const s8v*)(e1 + aoff);
    s8v af;
#pragma unroll
    for (int j = 0; j < 8; ++j)
      af[j] = (short)f2b(0.5f * (b2f((u16)a0[j]) + b2f((u16)a1[j])));
#pragma unroll
    for (int nt = 0; nt < 16; ++nt) {
      s8v bf = *(const s8v*)(WaT + (size_t)(nt * 16 + lm) * 512 + ks * 32 + qk * 8);
      acc[nt] = __builtin_amdgcn_mfma_f32_16x16x32_bf16(af, bf, acc[nt], 0, 0, 0);
    }
  }

  float sums[4] = {0.f, 0.f, 0.f, 0.f};
#pragma unroll
  for (int nt = 0; nt < 16; ++nt) {
    int col = nt * 16 + lm;
    float bb = ba0[col];
    float al = alpha_a[col];
    float wv = Wa1[col];
#pragma unroll
    for (int r = 0; r < 4; ++r) {
      float v = acc[nt][r] + bb;
      v = (v >= 0.f) ? v : al * v;
      sums[r] += v * wv;
    }
  }
  float bb1 = ba1[0];
#pragma unroll
  for (int r = 0; r < 4; ++r) {
    float v = sums[r];
    v += __shfl_xor(v, 1, 16);
    v += __shfl_xor(v, 2, 16);
    v += __shfl_xor(v, 4, 16);
    v += __shfl_xor(v, 8, 16);
    if (lm == 0) {
      int b = 16 * w + qk * 4 + r;
      scores[(size_t)b * 256 + t] = v + bb1;
    }
  }
}

// ---------------------------------------------------------------------------
// Softmax over T + pooled[b][u] = sum_t w[t]*enc[b][t][u]
// ---------------------------------------------------------------------------
__global__ __launch_bounds__(256) void attn_pool(
    const u16* __restrict__ out3, const float* __restrict__ scores,
    u16* __restrict__ pooled)
{
  __shared__ float red[256];
  __shared__ float wts[256];
  int b = blockIdx.x, tid = threadIdx.x;
  float s = scores[(size_t)b * 256 + tid];
  red[tid] = s; __syncthreads();
  for (int o = 128; o > 0; o >>= 1) { if (tid < o) red[tid] = fmaxf(red[tid], red[tid + o]); __syncthreads(); }
  float m = red[0]; __syncthreads();
  float e = __expf(s - m);
  red[tid] = e; __syncthreads();
  for (int o = 128; o > 0; o >>= 1) { if (tid < o) red[tid] += red[tid + o]; __syncthreads(); }
  float inv = 1.f / red[0];
  wts[tid] = e * inv; __syncthreads();

  int u2 = tid * 2;
  float a0 = 0.f, a1 = 0.f;
#pragma unroll 4
  for (int t = 0; t < 256; ++t) {
    float wt = wts[t];
    const ushort2 v0 = *(const ushort2*)(out3 + ((size_t)t * 64 + b) * 512 + u2);
    const ushort2 v1 = *(const ushort2*)(out3 + (((size_t)256 + t) * 64 + b) * 512 + u2);
    a0 += wt * 0.5f * (b2f(v0.x) + b2f(v1.x));
    a1 += wt * 0.5f * (b2f(v0.y) + b2f(v1.y));
  }
  pooled[(size_t)b * 512 + u2] = f2b(a0);
  pooled[(size_t)b * 512 + u2 + 1] = f2b(a1);
}

// ---------------------------------------------------------------------------
// Head: h = prelu(BN(pooled@Wd0+bd0)); out = softmax(h@Wd1+bd1)  (float out)
// ---------------------------------------------------------------------------
__global__ __launch_bounds__(256) void head(
    const u16* __restrict__ pooled, const u16* __restrict__ WdT,
    const float* __restrict__ bd0, const float* __restrict__ gamma,
    const float* __restrict__ beta, const float* __restrict__ bn_mean,
    const float* __restrict__ bn_var, const float* __restrict__ alpha_h,
    const float* __restrict__ Wd1, const float* __restrict__ bd1,
    float* __restrict__ outp)
{
  __shared__ float hl[64][260];
  __shared__ float lg[64][8];
  int tid = threadIdx.x;
  int w = tid >> 6, lane = tid & 63, lm = lane & 15, qk = lane >> 4;
  const f4v fzero = {0.f, 0.f, 0.f, 0.f};
  f4v acc[16];
#pragma unroll
  for (int nt = 0; nt < 16; ++nt) acc[nt] = fzero;
  for (int ks = 0; ks < 16; ++ks) {
    s8v a = *(const s8v*)(pooled + (size_t)(16 * w + lm) * 512 + ks * 32 + qk * 8);
#pragma unroll
    for (int nt = 0; nt < 16; ++nt) {
      s8v bf = *(const s8v*)(WdT + (size_t)(nt * 16 + lm) * 512 + ks * 32 + qk * 8);
      acc[nt] = __builtin_amdgcn_mfma_f32_16x16x32_bf16(a, bf, acc[nt], 0, 0, 0);
    }
  }
#pragma unroll
  for (int nt = 0; nt < 16; ++nt) {
    int col = nt * 16 + lm;
    float mn = bn_mean[col];
    float sc = gamma[col] * rsqrtf(bn_var[col] + 1e-3f);
    float be = beta[col];
    float al = alpha_h[col];
    float b0 = bd0[col];
#pragma unroll
    for (int r = 0; r < 4; ++r) {
      float v = acc[nt][r] + b0;
      v = (v - mn) * sc + be;
      v = (v >= 0.f) ? v : al * v;
      hl[16 * w + qk * 4 + r][col] = v;
    }
  }
  __syncthreads();
  for (int idx = tid; idx < 448; idx += 256) {
    int b = idx / 7, cc = idx - b * 7;
    float sv = bd1[cc];
    for (int k = 0; k < 256; ++k) sv += hl[b][k] * Wd1[k * 7 + cc];
    lg[b][cc] = sv;
  }
  __syncthreads();
  if (tid < 64) {
    float mx = -1e30f;
#pragma unroll
    for (int cc = 0; cc < 7; ++cc) mx = fmaxf(mx, lg[tid][cc]);
    float sum = 0.f; float ex[7];
#pragma unroll
    for (int cc = 0; cc < 7; ++cc) { ex[cc] = __expf(lg[tid][cc] - mx); sum += ex[cc]; }
    float inv = 1.f / sum;
#pragma unroll
    for (int cc = 0; cc < 7; ++cc) outp[tid * 7 + cc] = ex[cc] * inv;
  }
}

// ---------------------------------------------------------------------------
extern "C" void kernel_launch(void* const* d_in, const int* in_sizes, int n_in,
                              void* d_out, int out_size, void* d_ws, size_t ws_size,
                              hipStream_t stream)
{
  (void)in_sizes; (void)n_in; (void)out_size; (void)ws_size;
  const int*   ids     = (const int*)d_in[0];
  const float* emb     = (const float*)d_in[1];
  const float* k0      = (const float*)d_in[2];
  const float* k12     = (const float*)d_in[3];
  const float* rec     = (const float*)d_in[4];
  const float* bias    = (const float*)d_in[5];
  const float* Wa0     = (const float*)d_in[6];
  const float* ba0     = (const float*)d_in[7];
  const float* alpha_a = (const float*)d_in[8];
  const float* Wa1     = (const float*)d_in[9];
  const float* ba1     = (const float*)d_in[10];
  const float* Wd0     = (const float*)d_in[11];
  const float* bd0     = (const float*)d_in[12];
  const float* gamma   = (const float*)d_in[13];
  const float* beta    = (const float*)d_in[14];
  const float* bn_mean = (const float*)d_in[15];
  const float* bn_var  = (const float*)d_in[16];
  const float* alpha_h = (const float*)d_in[17];
  const float* Wd1     = (const float*)d_in[18];
  const float* bd1     = (const float*)d_in[19];

  char* ws = (char*)d_ws;
  // out3 (33,554,432 B) ALIASES WT (25,165,824 B): WT is dead once lstm_main's
  // prologue barrier passes (B-frags register-resident); out3 writes start after.
  u16* WT      = (u16*)(ws);                    // [0, 25.17 MB)
  u16* out3    = (u16*)(ws);                    // [0, 33.55 MB)
  u16* hist    = (u16*)(ws + 33554432);         // 32*6*64*512*2 = 12,582,912
  u16* WaT     = (u16*)(ws + 46137344);         // 262,144
  u16* WdT     = (u16*)(ws + 46399488);         // 262,144
  float* scores= (float*)(ws + 46661632);       // 65,536
  u16* pooled  = (u16*)(ws + 46727168);         // 65,536
  u16* zbuf    = (u16*)(ws + 46792704);         // 65,536 (zero tile)
  unsigned* bar= (unsigned*)(ws + 46858240);    // [0]=prologue counter, +16: 192 flags
                                                // total 46,859,264 B

  hipMemsetAsync(zbuf, 0, 65536, stream);
  hipMemsetAsync(bar, 0, 1024, stream);

  prep_weights<<<dim3(3136), dim3(256), 0, stream>>>(k0, k12, rec, Wa0, Wd0, WT, WaT, WdT);

  void* args[] = { (void*)&WT, (void*)&emb, (void*)&ids, (void*)&bias,
                   (void*)&hist, (void*)&zbuf, (void*)&out3, (void*)&bar };
  hipLaunchCooperativeKernel((void*)lstm_main, dim3(NBLK), dim3(256), args, 0, stream);

  attn_scores<<<dim3(256), dim3(256), 0, stream>>>(out3, WaT, ba0, alpha_a, Wa1, ba1, scores);
  attn_pool<<<dim3(64), dim3(256), 0, stream>>>(out3, scores, pooled);
  head<<<dim3(1), dim3(256), 0, stream>>>(pooled, WdT, bd0, gamma, beta, bn_mean, bn_var,
                                          alpha_h, Wd1, bd1, (float*)d_out);
}